// Round 2
// baseline (2368.108 us; speedup 1.0000x reference)
//
#include <hip/hip_runtime.h>
#include <math.h>

#define N 8192
#define D 512
#define KSEL 20
#define CAND_CAP 256
#define WINDOW 6e-3f

// ---------------------------------------------------------------------------
// K1: emulate numpy float32 prep per row:
//   norm  = fl32(sqrt(pairwise_sum(fl32(f_k^2))))   (numpy pairwise, n=512)
//   sqf   = fl32(fl32(x*x) + fl32(y*y))
//   out[N*N] = fl32 sigmoid(lambda_weight)
// ---------------------------------------------------------------------------
__global__ __launch_bounds__(256) void prep_kernel(
    const float* __restrict__ feat, const float* __restrict__ pos,
    const float* __restrict__ lamw,
    float* __restrict__ normf, float* __restrict__ sqf,
    float* __restrict__ out) {
  int row = blockIdx.x * 256 + threadIdx.x;
  if (row >= N) return;
  const float* f = feat + (size_t)row * D;
  // numpy pairwise_sum over 512 contiguous fp32 squares:
  // 512 -> 256+256 -> each 128+128; each 128 block: 8 accumulators.
  float part[4];
  #pragma unroll
  for (int b = 0; b < 4; b++) {
    const float* a = f + b * 128;
    float r[8];
    #pragma unroll
    for (int j = 0; j < 8; j++) r[j] = __fmul_rn(a[j], a[j]);
    for (int i = 8; i < 128; i += 8) {
      #pragma unroll
      for (int j = 0; j < 8; j++)
        r[j] = __fadd_rn(r[j], __fmul_rn(a[i + j], a[i + j]));
    }
    part[b] = __fadd_rn(__fadd_rn(__fadd_rn(r[0], r[1]), __fadd_rn(r[2], r[3])),
                        __fadd_rn(__fadd_rn(r[4], r[5]), __fadd_rn(r[6], r[7])));
  }
  float s = __fadd_rn(__fadd_rn(part[0], part[1]), __fadd_rn(part[2], part[3]));
  float nrm = fmaxf(__fsqrt_rn(s), 1e-12f);
  normf[row] = nrm;
  float x = pos[2 * row], y = pos[2 * row + 1];
  sqf[row] = __fadd_rn(__fmul_rn(x, x), __fmul_rn(y, y));
  if (row == 0) {
    float e = (float)exp(-(double)lamw[0]);
    out[(size_t)N * N] = 1.0f / __fadd_rn(1.0f, e);
  }
}

// ---------------------------------------------------------------------------
// K2: fp32 approximate adjacency (dense) for candidate FILTERING only.
// Accuracy needed: |filter - np_fp32| << WINDOW (6e-3). fp32 tiled GEMM with
// sequential-k accumulation gives ~1e-4 worst case. 128x128 tile, BK=8.
// ---------------------------------------------------------------------------
__global__ __launch_bounds__(256) void adj_kernel(
    const float* __restrict__ feat, const float* __restrict__ pos,
    const float* __restrict__ normf, const float* __restrict__ sqf,
    const float* __restrict__ lamw, const float* __restrict__ temp,
    float* __restrict__ out) {
  __shared__ float As[8][128];
  __shared__ float Bs[8][128];
  int bx = blockIdx.x, by = blockIdx.y;
  int tid = threadIdx.x;
  int tx = tid & 15, ty = tid >> 4;
  int lr = tid >> 1;
  int lc = (tid & 1) * 4;
  int arow = by * 128 + lr, brow = bx * 128 + lr;
  float ia = 1.0f / normf[arow], ib = 1.0f / normf[brow];
  const float* af = feat + (size_t)arow * D;
  const float* bf = feat + (size_t)brow * D;

  float acc[8][8];
  #pragma unroll
  for (int r = 0; r < 8; r++)
    #pragma unroll
    for (int c = 0; c < 8; c++) acc[r][c] = 0.f;

  for (int k0 = 0; k0 < D; k0 += 8) {
    float4 a4 = *(const float4*)(af + k0 + lc);
    float4 b4 = *(const float4*)(bf + k0 + lc);
    As[lc + 0][lr] = a4.x * ia; As[lc + 1][lr] = a4.y * ia;
    As[lc + 2][lr] = a4.z * ia; As[lc + 3][lr] = a4.w * ia;
    Bs[lc + 0][lr] = b4.x * ib; Bs[lc + 1][lr] = b4.y * ib;
    Bs[lc + 2][lr] = b4.z * ib; Bs[lc + 3][lr] = b4.w * ib;
    __syncthreads();
    #pragma unroll
    for (int kk = 0; kk < 8; kk++) {
      float a[8], b[8];
      #pragma unroll
      for (int r = 0; r < 8; r++) a[r] = As[kk][ty * 8 + r];
      #pragma unroll
      for (int c = 0; c < 8; c++) b[c] = Bs[kk][tx + c * 16];
      #pragma unroll
      for (int r = 0; r < 8; r++)
        #pragma unroll
        for (int c = 0; c < 8; c++) acc[r][c] += a[r] * b[c];
    }
    __syncthreads();
  }

  float lam = 1.f / (1.f + __expf(-lamw[0]));
  float T = temp[0];
  float oml = 1.f - lam;
  float px[8], py[8], sqr[8], qx[8], qy[8], sqc[8];
  #pragma unroll
  for (int r = 0; r < 8; r++) {
    int gi = by * 128 + ty * 8 + r;
    px[r] = pos[2 * gi]; py[r] = pos[2 * gi + 1]; sqr[r] = sqf[gi];
  }
  #pragma unroll
  for (int c = 0; c < 8; c++) {
    int gj = bx * 128 + tx + c * 16;
    qx[c] = pos[2 * gj]; qy[c] = pos[2 * gj + 1]; sqc[c] = sqf[gj];
  }
  #pragma unroll
  for (int r = 0; r < 8; r++) {
    int gi = by * 128 + ty * 8 + r;
    float* orow = out + (size_t)gi * N + bx * 128;
    #pragma unroll
    for (int c = 0; c < 8; c++) {
      float d2 = fmaxf(sqr[r] + sqc[c] - 2.f * (px[r] * qx[c] + py[r] * qy[c]), 0.f);
      float sp = __expf(-d2 * (1.f / 5000.f));
      float u = lam * acc[r][c] + oml * sp;
      orow[tx + c * 16] = 1.f / (1.f + __expf(-u * T));
    }
  }
}

// ---------------------------------------------------------------------------
// K3: per-row exact top-20 under emulated-numpy-fp32 arithmetic.
//  1) approx top-20 on filter values (exact iterative argmax, tie->low idx)
//  2) candidates = approx top-20 + all filter vals >= t20 - WINDOW
//  3) per candidate: bit-emulate np fp32 value:
//       a_k = fl(f_ik / norm_i), b_k = fl(f_jk / norm_j)
//       sim = sequential fmaf chain k=0..511  (BLAS sgemm microkernel order)
//       dot2 = fmaf(yi,yj, fl(xi*xj)); d2 = fl(fl(sqi+sqj) - 2*dot2), max 0
//       sp = fl32(exp(fl(-d2/5000)));  u = fl(fl(lam*sim)+fl(oml*sp))*T
//       adj = fl(1/fl(1+fl32(exp(-u))))
//  4) select top-20 on fp32 value desc, index asc (lax.top_k tie semantics)
//  5) write row: emulated value at selected, 0 elsewhere
// ---------------------------------------------------------------------------
__global__ __launch_bounds__(256) void topk_kernel(
    const float* __restrict__ feat, const float* __restrict__ pos,
    const float* __restrict__ normf, const float* __restrict__ sqf,
    const float* __restrict__ lamw, const float* __restrict__ temp,
    float* __restrict__ out) {
  __shared__ float vals[N];        // 32 KB
  __shared__ float ai[D];          // np-exact normalized row i
  __shared__ float rv[4];
  __shared__ int   ri[4];
  __shared__ int   candIdx[CAND_CAP];
  __shared__ float candV[CAND_CAP];
  __shared__ int   selIdx[KSEL];
  __shared__ float selVal[KSEL];
  __shared__ int cnt;

  int row = blockIdx.x, t = threadIdx.x;
  float* orow = out + (size_t)row * N;
  const float* fi = feat + (size_t)row * D;
  float n_i = normf[row];
  for (int j = t; j < N; j += 256) vals[j] = orow[j];
  for (int k = t; k < D; k += 256) ai[k] = fi[k] / n_i;   // correctly-rounded div = np
  __syncthreads();

  // --- approx top-20 on filter values ---
  float t20 = 0.f;
  for (int it = 0; it < KSEL; ++it) {
    float best = -1.f; int bi = N;
    for (int j = t; j < N; j += 256) {
      float v = vals[j];
      if (v > best) { best = v; bi = j; }
    }
    #pragma unroll
    for (int off = 32; off > 0; off >>= 1) {
      float ov = __shfl_down(best, off, 64);
      int   oi = __shfl_down(bi, off, 64);
      if (ov > best || (ov == best && oi < bi)) { best = ov; bi = oi; }
    }
    int wid = t >> 6;
    if ((t & 63) == 0) { rv[wid] = best; ri[wid] = bi; }
    __syncthreads();
    if (t == 0) {
      float bv = rv[0]; int bj = ri[0];
      for (int w = 1; w < 4; w++)
        if (rv[w] > bv || (rv[w] == bv && ri[w] < bj)) { bv = rv[w]; bj = ri[w]; }
      candIdx[it] = bj;
      vals[bj] = -2.f;
      rv[0] = bv;
    }
    __syncthreads();
    if (it == KSEL - 1) t20 = rv[0];
  }

  // --- candidate sweep ---
  if (t == 0) cnt = KSEL;
  __syncthreads();
  float thr = t20 - WINDOW;
  for (int j = t; j < N; j += 256) {
    if (vals[j] >= thr) {
      int p = atomicAdd(&cnt, 1);
      if (p < CAND_CAP) candIdx[p] = j;
    }
  }
  __syncthreads();
  int ncand = min(cnt, CAND_CAP);

  // --- emulated-np-fp32 recompute: one thread per candidate ---
  float lamf;
  { float e = (float)exp(-(double)lamw[0]); lamf = 1.0f / __fadd_rn(1.0f, e); }
  float omlf = __fadd_rn(1.0f, -lamf);     // exact (Sterbenz)
  float Tf = temp[0];
  float sq_i = sqf[row];
  float xi = pos[2 * row], yi = pos[2 * row + 1];
  for (int ci = t; ci < ncand; ci += 256) {
    int j = candIdx[ci];
    const float* fj = feat + (size_t)j * D;
    float n_j = normf[j];
    float acc = 0.0f;
    for (int k = 0; k < D; k++) {
      float b = fj[k] / n_j;                 // np broadcast division rounding
      acc = __fmaf_rn(ai[k], b, acc);        // sequential-k FMA (sgemm order)
    }
    float xj = pos[2 * j], yj = pos[2 * j + 1];
    float dot2 = __fmaf_rn(yi, yj, __fmul_rn(xi, xj));   // sgemm k=2
    float S = __fadd_rn(sq_i, sqf[j]);
    float d2 = fmaxf(__fadd_rn(S, -__fmul_rn(2.0f, dot2)), 0.0f);  // 2*dot exact
    float arg = (-d2) / 5000.0f;
    float sp = (float)exp((double)arg);      // correctly-rounded fp32 exp proxy
    float u = __fmul_rn(__fadd_rn(__fmul_rn(lamf, acc), __fmul_rn(omlf, sp)), Tf);
    float e = (float)exp(-(double)u);
    candV[ci] = 1.0f / __fadd_rn(1.0f, e);
  }
  __syncthreads();

  // --- exact selection on fp32 values (desc), index asc tie-break ---
  if (t == 0) {
    for (int s = 0; s < KSEL; s++) {
      float bu = -1.0f; int bi = N, bc = 0;
      for (int c = 0; c < ncand; c++) {
        float u = candV[c]; int j = candIdx[c];
        if (u > bu || (u == bu && j < bi)) { bu = u; bi = j; bc = c; }
      }
      selIdx[s] = bi; selVal[s] = bu; candV[bc] = -1.0f;
    }
  }
  __syncthreads();

  // --- masked write ---
  for (int j = t; j < N; j += 256) {
    float o = 0.f;
    #pragma unroll
    for (int s = 0; s < KSEL; s++)
      if (selIdx[s] == j) o = selVal[s];
    orow[j] = o;
  }
}

extern "C" void kernel_launch(void* const* d_in, const int* in_sizes, int n_in,
                              void* d_out, int out_size, void* d_ws, size_t ws_size,
                              hipStream_t stream) {
  const float* feat = (const float*)d_in[0];
  const float* pos  = (const float*)d_in[1];
  const float* lamw = (const float*)d_in[2];
  const float* temp = (const float*)d_in[3];
  float* out = (float*)d_out;
  float* normf = (float*)d_ws;         // 8192 floats
  float* sqf   = normf + N;            // 8192 floats

  prep_kernel<<<(N + 255) / 256, 256, 0, stream>>>(feat, pos, lamw, normf, sqf, out);
  dim3 g(N / 128, N / 128);
  adj_kernel<<<g, 256, 0, stream>>>(feat, pos, normf, sqf, lamw, temp, out);
  topk_kernel<<<N, 256, 0, stream>>>(feat, pos, normf, sqf, lamw, temp, out);
}

// Round 3
// 1397.177 us; speedup vs baseline: 1.6949x; 1.6949x over previous
//
#include <hip/hip_runtime.h>
#include <math.h>

#define N 8192
#define D 512
#define KSEL 20
#define CAND_CAP 512
#define WINDOW 2e-3f

typedef __attribute__((ext_vector_type(8))) short short8;
typedef __attribute__((ext_vector_type(4))) float f32x4;

__device__ __forceinline__ unsigned short f2bf(float x) {
  unsigned int u = __float_as_uint(x);
  unsigned int r = u + 0x7FFFu + ((u >> 16) & 1u);   // RNE to bf16
  return (unsigned short)(r >> 16);
}

// ---------------------------------------------------------------------------
// K1: emulate numpy float32 prep per row (unchanged from R2 — bit-exact):
//   norm = fl32(sqrt(pairwise_sum(fl32(f_k^2)))), sqf, out[N*N]=sigmoid(lam)
// ---------------------------------------------------------------------------
__global__ __launch_bounds__(256) void prep_kernel(
    const float* __restrict__ feat, const float* __restrict__ pos,
    const float* __restrict__ lamw,
    float* __restrict__ normf, float* __restrict__ sqf,
    float* __restrict__ out) {
  int row = blockIdx.x * 256 + threadIdx.x;
  if (row >= N) return;
  const float* f = feat + (size_t)row * D;
  float part[4];
  #pragma unroll
  for (int b = 0; b < 4; b++) {
    const float* a = f + b * 128;
    float r[8];
    #pragma unroll
    for (int j = 0; j < 8; j++) r[j] = __fmul_rn(a[j], a[j]);
    for (int i = 8; i < 128; i += 8) {
      #pragma unroll
      for (int j = 0; j < 8; j++)
        r[j] = __fadd_rn(r[j], __fmul_rn(a[i + j], a[i + j]));
    }
    part[b] = __fadd_rn(__fadd_rn(__fadd_rn(r[0], r[1]), __fadd_rn(r[2], r[3])),
                        __fadd_rn(__fadd_rn(r[4], r[5]), __fadd_rn(r[6], r[7])));
  }
  float s = __fadd_rn(__fadd_rn(part[0], part[1]), __fadd_rn(part[2], part[3]));
  float nrm = fmaxf(__fsqrt_rn(s), 1e-12f);
  normf[row] = nrm;
  float x = pos[2 * row], y = pos[2 * row + 1];
  sqf[row] = __fadd_rn(__fmul_rn(x, x), __fmul_rn(y, y));
  if (row == 0) {
    float e = (float)exp(-(double)lamw[0]);
    out[(size_t)N * N] = 1.0f / __fadd_rn(1.0f, e);
  }
}

// ---------------------------------------------------------------------------
// K2: bf16-MFMA approximate adjacency (dense) for candidate FILTERING only.
// |filter - np_fp32| <= ~4e-4 worst case << WINDOW (2e-3). adj is symmetric,
// and final values come from np-exact emulation, so operand-layout mistakes
// cannot corrupt the output — only the filter quality.
// 128x128 tile, BK=32, 256 threads = 4 waves, each wave 64x64 (4x4 MFMA frags).
// ---------------------------------------------------------------------------
__global__ __launch_bounds__(256) void adj_kernel(
    const float* __restrict__ feat, const float* __restrict__ pos,
    const float* __restrict__ normf, const float* __restrict__ sqf,
    const float* __restrict__ lamw, const float* __restrict__ temp,
    float* __restrict__ out) {
  __shared__ unsigned short As[128][40];   // +8 pad: 80B row stride, 16B aligned
  __shared__ unsigned short Bs[128][40];
  int bx = blockIdx.x, by = blockIdx.y;
  int tid = threadIdx.x;
  int wave = tid >> 6, lane = tid & 63;
  int wr = (wave >> 1) * 64, wc = (wave & 1) * 64;
  int m = lane & 15, quad = lane >> 4;

  // staging assignment: 2 threads per row, each half (16 elems of K)
  int sr = tid >> 1;
  int k0 = (tid & 1) * 16;
  int arow = by * 128 + sr, brow = bx * 128 + sr;
  float ia = 1.0f / normf[arow], ib = 1.0f / normf[brow];
  const float* af = feat + (size_t)arow * D + k0;
  const float* bf = feat + (size_t)brow * D + k0;

  f32x4 acc[4][4];
  #pragma unroll
  for (int i = 0; i < 4; i++)
    #pragma unroll
    for (int j = 0; j < 4; j++) acc[i][j] = (f32x4){0.f, 0.f, 0.f, 0.f};

  for (int kt = 0; kt < D / 32; kt++) {
    const float* pA = af + kt * 32;
    const float* pB = bf + kt * 32;
    float4 a0 = *(const float4*)(pA);     float4 a1 = *(const float4*)(pA + 4);
    float4 a2 = *(const float4*)(pA + 8); float4 a3 = *(const float4*)(pA + 12);
    float4 b0 = *(const float4*)(pB);     float4 b1 = *(const float4*)(pB + 4);
    float4 b2 = *(const float4*)(pB + 8); float4 b3 = *(const float4*)(pB + 12);
    short8 wa0, wa1, wb0, wb1;
    wa0[0]=f2bf(a0.x*ia); wa0[1]=f2bf(a0.y*ia); wa0[2]=f2bf(a0.z*ia); wa0[3]=f2bf(a0.w*ia);
    wa0[4]=f2bf(a1.x*ia); wa0[5]=f2bf(a1.y*ia); wa0[6]=f2bf(a1.z*ia); wa0[7]=f2bf(a1.w*ia);
    wa1[0]=f2bf(a2.x*ia); wa1[1]=f2bf(a2.y*ia); wa1[2]=f2bf(a2.z*ia); wa1[3]=f2bf(a2.w*ia);
    wa1[4]=f2bf(a3.x*ia); wa1[5]=f2bf(a3.y*ia); wa1[6]=f2bf(a3.z*ia); wa1[7]=f2bf(a3.w*ia);
    wb0[0]=f2bf(b0.x*ib); wb0[1]=f2bf(b0.y*ib); wb0[2]=f2bf(b0.z*ib); wb0[3]=f2bf(b0.w*ib);
    wb0[4]=f2bf(b1.x*ib); wb0[5]=f2bf(b1.y*ib); wb0[6]=f2bf(b1.z*ib); wb0[7]=f2bf(b1.w*ib);
    wb1[0]=f2bf(b2.x*ib); wb1[1]=f2bf(b2.y*ib); wb1[2]=f2bf(b2.z*ib); wb1[3]=f2bf(b2.w*ib);
    wb1[4]=f2bf(b3.x*ib); wb1[5]=f2bf(b3.y*ib); wb1[6]=f2bf(b3.z*ib); wb1[7]=f2bf(b3.w*ib);
    *(short8*)&As[sr][k0]     = wa0;
    *(short8*)&As[sr][k0 + 8] = wa1;
    *(short8*)&Bs[sr][k0]     = wb0;
    *(short8*)&Bs[sr][k0 + 8] = wb1;
    __syncthreads();

    short8 fa[4], fb[4];
    #pragma unroll
    for (int ti = 0; ti < 4; ti++)
      fa[ti] = *(const short8*)&As[wr + ti * 16 + m][quad * 8];
    #pragma unroll
    for (int tj = 0; tj < 4; tj++)
      fb[tj] = *(const short8*)&Bs[wc + tj * 16 + m][quad * 8];
    #pragma unroll
    for (int ti = 0; ti < 4; ti++)
      #pragma unroll
      for (int tj = 0; tj < 4; tj++)
        acc[ti][tj] = __builtin_amdgcn_mfma_f32_16x16x32_bf16(
            fa[ti], fb[tj], acc[ti][tj], 0, 0, 0);
    __syncthreads();
  }

  // epilogue: spatial + blend + sigmoid, fp32 (filter precision only)
  float lam = 1.f / (1.f + __expf(-lamw[0]));
  float T = temp[0];
  float oml = 1.f - lam;
  #pragma unroll
  for (int ti = 0; ti < 4; ti++) {
    int gi0 = by * 128 + wr + ti * 16 + quad * 4;
    float xi[4], yi[4], sqi[4];
    #pragma unroll
    for (int r = 0; r < 4; r++) {
      int gi = gi0 + r;
      xi[r] = pos[2 * gi]; yi[r] = pos[2 * gi + 1]; sqi[r] = sqf[gi];
    }
    #pragma unroll
    for (int tj = 0; tj < 4; tj++) {
      int gj = bx * 128 + wc + tj * 16 + m;
      float xj = pos[2 * gj], yj = pos[2 * gj + 1], sj = sqf[gj];
      f32x4 c = acc[ti][tj];
      #pragma unroll
      for (int r = 0; r < 4; r++) {
        float d2 = fmaxf(sqi[r] + sj - 2.f * (xi[r] * xj + yi[r] * yj), 0.f);
        float sp = __expf(-d2 * (1.f / 5000.f));
        float u = lam * c[r] + oml * sp;
        out[(size_t)(gi0 + r) * N + gj] = 1.f / (1.f + __expf(-u * T));
      }
    }
  }
}

// ---------------------------------------------------------------------------
// K3: per-row exact top-20 under emulated-numpy-fp32 arithmetic.
// Histogram(1024 bins) -> suffix-scan -> threshold bin (cnt_ge >= 20) ->
// candidates = vals >= lo_b - WINDOW -> np-exact fp32 emulation (frozen from
// R2, verified absmax 0.0) -> exact selection -> masked write via LDS.
// ---------------------------------------------------------------------------
__global__ __launch_bounds__(256) void topk_kernel(
    const float* __restrict__ feat, const float* __restrict__ pos,
    const float* __restrict__ normf, const float* __restrict__ sqf,
    const float* __restrict__ lamw, const float* __restrict__ temp,
    float* __restrict__ out) {
  __shared__ float vals[N];          // 32 KB
  __shared__ float ai[D];            // np-exact normalized row i
  __shared__ int   hist[1024];
  __shared__ int   S[256];
  __shared__ int   thrBin;
  __shared__ int   candIdx[CAND_CAP];
  __shared__ float candV[CAND_CAP];
  __shared__ int   selIdx[KSEL];
  __shared__ float selVal[KSEL];
  __shared__ int   cnt;

  int row = blockIdx.x, t = threadIdx.x;
  float* orow = out + (size_t)row * N;
  const float* fi = feat + (size_t)row * D;
  float n_i = normf[row];

  for (int j = 4 * t; j < N; j += 1024)
    *(float4*)&vals[j] = *(const float4*)&orow[j];
  for (int k = t; k < D; k += 256) ai[k] = fi[k] / n_i;  // correctly-rounded = np
  #pragma unroll
  for (int b = 0; b < 4; b++) hist[t + 256 * b] = 0;
  if (t == 0) { thrBin = 0; cnt = 0; }
  __syncthreads();

  // --- histogram ---
  for (int j = t; j < N; j += 256) {
    int bin = (int)(vals[j] * 1024.f);
    bin = max(0, min(1023, bin));
    atomicAdd(&hist[bin], 1);
  }
  __syncthreads();

  // --- suffix scan over 256 groups of 4 bins ---
  S[t] = hist[4 * t] + hist[4 * t + 1] + hist[4 * t + 2] + hist[4 * t + 3];
  __syncthreads();
  for (int st = 1; st < 256; st <<= 1) {
    int add = (t + st < 256) ? S[t + st] : 0;
    __syncthreads();
    S[t] += add;
    __syncthreads();
  }
  {
    int tail = (t < 255) ? S[t + 1] : 0;
    int h0 = hist[4 * t], h1 = hist[4 * t + 1], h2 = hist[4 * t + 2], h3 = hist[4 * t + 3];
    int g3 = tail + h3;
    int g2 = g3 + h2;
    int g1 = g2 + h1;
    int g0 = g1 + h0;
    int best = -1;
    if      (g3 >= KSEL) best = 4 * t + 3;
    else if (g2 >= KSEL) best = 4 * t + 2;
    else if (g1 >= KSEL) best = 4 * t + 1;
    else if (g0 >= KSEL) best = 4 * t;
    if (best >= 0) atomicMax(&thrBin, best);
  }
  __syncthreads();

  // lo_b <= filter_t20 < lo_b + 1/1024; candidates >= lo_b - WINDOW
  float thr = (float)thrBin * (1.0f / 1024.f) - WINDOW;

  // --- candidate sweep ---
  for (int j = t; j < N; j += 256) {
    if (vals[j] >= thr) {
      int p = atomicAdd(&cnt, 1);
      if (p < CAND_CAP) candIdx[p] = j;
    }
  }
  __syncthreads();
  int ncand = min(cnt, CAND_CAP);

  // --- emulated-np-fp32 recompute (FROZEN from R2 — verified bit-exact) ---
  float lamf;
  { float e = (float)exp(-(double)lamw[0]); lamf = 1.0f / __fadd_rn(1.0f, e); }
  float omlf = __fadd_rn(1.0f, -lamf);
  float Tf = temp[0];
  float sq_i = sqf[row];
  float xi = pos[2 * row], yi = pos[2 * row + 1];
  for (int ci = t; ci < ncand; ci += 256) {
    int j = candIdx[ci];
    const float* fj = feat + (size_t)j * D;
    float n_j = normf[j];
    float acc = 0.0f;
    for (int k = 0; k < D; k++) {
      float b = fj[k] / n_j;
      acc = __fmaf_rn(ai[k], b, acc);
    }
    float xj = pos[2 * j], yj = pos[2 * j + 1];
    float dot2 = __fmaf_rn(yi, yj, __fmul_rn(xi, xj));
    float Ssum = __fadd_rn(sq_i, sqf[j]);
    float d2 = fmaxf(__fadd_rn(Ssum, -__fmul_rn(2.0f, dot2)), 0.0f);
    float arg = (-d2) / 5000.0f;
    float sp = (float)exp((double)arg);
    float u = __fmul_rn(__fadd_rn(__fmul_rn(lamf, acc), __fmul_rn(omlf, sp)), Tf);
    float e = (float)exp(-(double)u);
    candV[ci] = 1.0f / __fadd_rn(1.0f, e);
  }
  __syncthreads();

  // --- exact selection: fp32 value desc, index asc tie-break ---
  if (t == 0) {
    for (int s = 0; s < KSEL; s++) {
      float bu = -1.0f; int bi = N, bc = 0;
      for (int c = 0; c < ncand; c++) {
        float u = candV[c]; int j = candIdx[c];
        if (u > bu || (u == bu && j < bi)) { bu = u; bi = j; bc = c; }
      }
      selIdx[s] = bi; selVal[s] = bu; candV[bc] = -1.0f;
    }
  }
  __syncthreads();

  // --- masked write via LDS (race-free), float4 streams ---
  float4 z4 = {0.f, 0.f, 0.f, 0.f};
  for (int j = 4 * t; j < N; j += 1024) *(float4*)&vals[j] = z4;
  __syncthreads();
  if (t < KSEL) vals[selIdx[t]] = selVal[t];
  __syncthreads();
  for (int j = 4 * t; j < N; j += 1024)
    *(float4*)&orow[j] = *(const float4*)&vals[j];
}

extern "C" void kernel_launch(void* const* d_in, const int* in_sizes, int n_in,
                              void* d_out, int out_size, void* d_ws, size_t ws_size,
                              hipStream_t stream) {
  const float* feat = (const float*)d_in[0];
  const float* pos  = (const float*)d_in[1];
  const float* lamw = (const float*)d_in[2];
  const float* temp = (const float*)d_in[3];
  float* out = (float*)d_out;
  float* normf = (float*)d_ws;         // 8192 floats
  float* sqf   = normf + N;            // 8192 floats

  prep_kernel<<<(N + 255) / 256, 256, 0, stream>>>(feat, pos, lamw, normf, sqf, out);
  dim3 g(N / 128, N / 128);
  adj_kernel<<<g, 256, 0, stream>>>(feat, pos, normf, sqf, lamw, temp, out);
  topk_kernel<<<N, 256, 0, stream>>>(feat, pos, normf, sqf, lamw, temp, out);
}

// Round 4
// 910.458 us; speedup vs baseline: 2.6010x; 1.5346x over previous
//
#include <hip/hip_runtime.h>
#include <math.h>

#define N 8192
#define D 512
#define KSEL 20
#define CAND_CAP 512
#define WINDOW 2e-3f

typedef __attribute__((ext_vector_type(8))) short short8;
typedef __attribute__((ext_vector_type(4))) float f32x4;

__device__ __forceinline__ unsigned short f2bf(float x) {
  unsigned int u = __float_as_uint(x);
  unsigned int r = u + 0x7FFFu + ((u >> 16) & 1u);   // RNE to bf16
  return (unsigned short)(r >> 16);
}

__device__ __forceinline__ void gld16(const unsigned short* g, unsigned short* l) {
  __builtin_amdgcn_global_load_lds(
      (const __attribute__((address_space(1))) unsigned int*)g,
      (__attribute__((address_space(3))) unsigned int*)l, 16, 0, 0);
}

// ---------------------------------------------------------------------------
// K1: emulate numpy float32 prep per row (FROZEN — verified bit-exact):
//   norm = fl32(sqrt(pairwise_sum(fl32(f_k^2)))), sqf, out[N*N]=sigmoid(lam)
// ---------------------------------------------------------------------------
__global__ __launch_bounds__(256) void prep_kernel(
    const float* __restrict__ feat, const float* __restrict__ pos,
    const float* __restrict__ lamw,
    float* __restrict__ normf, float* __restrict__ sqf,
    float* __restrict__ out) {
  int row = blockIdx.x * 256 + threadIdx.x;
  if (row >= N) return;
  const float* f = feat + (size_t)row * D;
  float part[4];
  #pragma unroll
  for (int b = 0; b < 4; b++) {
    const float* a = f + b * 128;
    float r[8];
    #pragma unroll
    for (int j = 0; j < 8; j++) r[j] = __fmul_rn(a[j], a[j]);
    for (int i = 8; i < 128; i += 8) {
      #pragma unroll
      for (int j = 0; j < 8; j++)
        r[j] = __fadd_rn(r[j], __fmul_rn(a[i + j], a[i + j]));
    }
    part[b] = __fadd_rn(__fadd_rn(__fadd_rn(r[0], r[1]), __fadd_rn(r[2], r[3])),
                        __fadd_rn(__fadd_rn(r[4], r[5]), __fadd_rn(r[6], r[7])));
  }
  float s = __fadd_rn(__fadd_rn(part[0], part[1]), __fadd_rn(part[2], part[3]));
  float nrm = fmaxf(__fsqrt_rn(s), 1e-12f);
  normf[row] = nrm;
  float x = pos[2 * row], y = pos[2 * row + 1];
  sqf[row] = __fadd_rn(__fmul_rn(x, x), __fmul_rn(y, y));
  if (row == 0) {
    float e = (float)exp(-(double)lamw[0]);
    out[(size_t)N * N] = 1.0f / __fadd_rn(1.0f, e);
  }
}

// ---------------------------------------------------------------------------
// K1b: bf16 normalized-feature matrix for the MFMA filter (filter-only
// precision; any reasonable rounding fine).
// ---------------------------------------------------------------------------
__global__ __launch_bounds__(256) void fnorm_kernel(
    const float* __restrict__ feat, const float* __restrict__ normf,
    unsigned short* __restrict__ fb) {
  int i0 = (blockIdx.x * 256 + threadIdx.x) * 4;
  float n = normf[i0 >> 9];
  float4 v = *(const float4*)(feat + i0);
  unsigned int lo = (unsigned int)f2bf(v.x / n) | ((unsigned int)f2bf(v.y / n) << 16);
  unsigned int hi = (unsigned int)f2bf(v.z / n) | ((unsigned int)f2bf(v.w / n) << 16);
  uint2 o; o.x = lo; o.y = hi;
  *(uint2*)(fb + i0) = o;
}

// ---------------------------------------------------------------------------
// K2 fast: bf16 MFMA filter GEMM from precomputed fnorm_bf16.
// 128x128 tile, BK=64, global_load_lds width=16, XOR-swizzled LDS
// (chunk stored at col (c+r)&7 -> frag reads are 2-way bank aliased = free).
// Filter precision only: |filter - np| ~ 5e-4 << WINDOW.
// ---------------------------------------------------------------------------
__global__ __launch_bounds__(256) void adj_fast(
    const unsigned short* __restrict__ G,
    const float* __restrict__ pos, const float* __restrict__ sqf,
    const float* __restrict__ lamw, const float* __restrict__ temp,
    float* __restrict__ out) {
  __shared__ __align__(16) unsigned short As[128 * 64];
  __shared__ __align__(16) unsigned short Bs[128 * 64];
  int bx = blockIdx.x, by = blockIdx.y;
  int tid = threadIdx.x;
  int wave = tid >> 6, lane = tid & 63;
  int wr = (wave >> 1) * 64, wc = (wave & 1) * 64;
  int m = lane & 15, quad = lane >> 4;

  f32x4 acc[4][4];
  #pragma unroll
  for (int i = 0; i < 4; i++)
    #pragma unroll
    for (int j = 0; j < 4; j++) acc[i][j] = (f32x4){0.f, 0.f, 0.f, 0.f};

  for (int kt = 0; kt < D / 64; kt++) {
    #pragma unroll
    for (int i = 0; i < 4; i++) {
      int f = i * 256 + tid;
      int r = f >> 3, c = f & 7;
      int cs = (c + r) & 7;
      size_t goff = (size_t)r * D + kt * 64 + cs * 8;
      gld16(G + (size_t)(by * 128) * D + goff, &As[f * 8]);
      gld16(G + (size_t)(bx * 128) * D + goff, &Bs[f * 8]);
    }
    __syncthreads();
    #pragma unroll
    for (int h = 0; h < 2; h++) {
      short8 fa[4], fb[4];
      #pragma unroll
      for (int ti = 0; ti < 4; ti++) {
        int row = wr + ti * 16 + m;
        int cc = ((h * 4 + quad) - row) & 7;
        fa[ti] = *(const short8*)&As[row * 64 + cc * 8];
      }
      #pragma unroll
      for (int tj = 0; tj < 4; tj++) {
        int row = wc + tj * 16 + m;
        int cc = ((h * 4 + quad) - row) & 7;
        fb[tj] = *(const short8*)&Bs[row * 64 + cc * 8];
      }
      #pragma unroll
      for (int ti = 0; ti < 4; ti++)
        #pragma unroll
        for (int tj = 0; tj < 4; tj++)
          acc[ti][tj] = __builtin_amdgcn_mfma_f32_16x16x32_bf16(
              fa[ti], fb[tj], acc[ti][tj], 0, 0, 0);
    }
    __syncthreads();
  }

  float lam = 1.f / (1.f + __expf(-lamw[0]));
  float T = temp[0];
  float oml = 1.f - lam;
  #pragma unroll
  for (int ti = 0; ti < 4; ti++) {
    int gi0 = by * 128 + wr + ti * 16 + quad * 4;
    float xi[4], yi[4], sqi[4];
    #pragma unroll
    for (int r = 0; r < 4; r++) {
      int gi = gi0 + r;
      xi[r] = pos[2 * gi]; yi[r] = pos[2 * gi + 1]; sqi[r] = sqf[gi];
    }
    #pragma unroll
    for (int tj = 0; tj < 4; tj++) {
      int gj = bx * 128 + wc + tj * 16 + m;
      float xj = pos[2 * gj], yj = pos[2 * gj + 1], sj = sqf[gj];
      f32x4 c = acc[ti][tj];
      #pragma unroll
      for (int r = 0; r < 4; r++) {
        float d2 = fmaxf(sqi[r] + sj - 2.f * (xi[r] * xj + yi[r] * yj), 0.f);
        float sp = __expf(-d2 * (1.f / 5000.f));
        float u = lam * c[r] + oml * sp;
        out[(size_t)(gi0 + r) * N + gj] = 1.f / (1.f + __expf(-u * T));
      }
    }
  }
}

// ---------------------------------------------------------------------------
// K2 slow (fallback if ws too small for fnorm_bf16): R3 adj kernel verbatim
// (proven correct/passing).
// ---------------------------------------------------------------------------
__global__ __launch_bounds__(256) void adj_slow(
    const float* __restrict__ feat, const float* __restrict__ pos,
    const float* __restrict__ normf, const float* __restrict__ sqf,
    const float* __restrict__ lamw, const float* __restrict__ temp,
    float* __restrict__ out) {
  __shared__ unsigned short As[128][40];
  __shared__ unsigned short Bs[128][40];
  int bx = blockIdx.x, by = blockIdx.y;
  int tid = threadIdx.x;
  int wave = tid >> 6, lane = tid & 63;
  int wr = (wave >> 1) * 64, wc = (wave & 1) * 64;
  int m = lane & 15, quad = lane >> 4;
  int sr = tid >> 1;
  int k0 = (tid & 1) * 16;
  int arow = by * 128 + sr, brow = bx * 128 + sr;
  float ia = 1.0f / normf[arow], ib = 1.0f / normf[brow];
  const float* af = feat + (size_t)arow * D + k0;
  const float* bf = feat + (size_t)brow * D + k0;

  f32x4 acc[4][4];
  #pragma unroll
  for (int i = 0; i < 4; i++)
    #pragma unroll
    for (int j = 0; j < 4; j++) acc[i][j] = (f32x4){0.f, 0.f, 0.f, 0.f};

  for (int kt = 0; kt < D / 32; kt++) {
    const float* pA = af + kt * 32;
    const float* pB = bf + kt * 32;
    float4 a0 = *(const float4*)(pA);     float4 a1 = *(const float4*)(pA + 4);
    float4 a2 = *(const float4*)(pA + 8); float4 a3 = *(const float4*)(pA + 12);
    float4 b0 = *(const float4*)(pB);     float4 b1 = *(const float4*)(pB + 4);
    float4 b2 = *(const float4*)(pB + 8); float4 b3 = *(const float4*)(pB + 12);
    short8 wa0, wa1, wb0, wb1;
    wa0[0]=f2bf(a0.x*ia); wa0[1]=f2bf(a0.y*ia); wa0[2]=f2bf(a0.z*ia); wa0[3]=f2bf(a0.w*ia);
    wa0[4]=f2bf(a1.x*ia); wa0[5]=f2bf(a1.y*ia); wa0[6]=f2bf(a1.z*ia); wa0[7]=f2bf(a1.w*ia);
    wa1[0]=f2bf(a2.x*ia); wa1[1]=f2bf(a2.y*ia); wa1[2]=f2bf(a2.z*ia); wa1[3]=f2bf(a2.w*ia);
    wa1[4]=f2bf(a3.x*ia); wa1[5]=f2bf(a3.y*ia); wa1[6]=f2bf(a3.z*ia); wa1[7]=f2bf(a3.w*ia);
    wb0[0]=f2bf(b0.x*ib); wb0[1]=f2bf(b0.y*ib); wb0[2]=f2bf(b0.z*ib); wb0[3]=f2bf(b0.w*ib);
    wb0[4]=f2bf(b1.x*ib); wb0[5]=f2bf(b1.y*ib); wb0[6]=f2bf(b1.z*ib); wb0[7]=f2bf(b1.w*ib);
    wb1[0]=f2bf(b2.x*ib); wb1[1]=f2bf(b2.y*ib); wb1[2]=f2bf(b2.z*ib); wb1[3]=f2bf(b2.w*ib);
    wb1[4]=f2bf(b3.x*ib); wb1[5]=f2bf(b3.y*ib); wb1[6]=f2bf(b3.z*ib); wb1[7]=f2bf(b3.w*ib);
    *(short8*)&As[sr][k0]     = wa0;
    *(short8*)&As[sr][k0 + 8] = wa1;
    *(short8*)&Bs[sr][k0]     = wb0;
    *(short8*)&Bs[sr][k0 + 8] = wb1;
    __syncthreads();
    short8 fa[4], fb[4];
    #pragma unroll
    for (int ti = 0; ti < 4; ti++)
      fa[ti] = *(const short8*)&As[wr + ti * 16 + m][quad * 8];
    #pragma unroll
    for (int tj = 0; tj < 4; tj++)
      fb[tj] = *(const short8*)&Bs[wc + tj * 16 + m][quad * 8];
    #pragma unroll
    for (int ti = 0; ti < 4; ti++)
      #pragma unroll
      for (int tj = 0; tj < 4; tj++)
        acc[ti][tj] = __builtin_amdgcn_mfma_f32_16x16x32_bf16(
            fa[ti], fb[tj], acc[ti][tj], 0, 0, 0);
    __syncthreads();
  }

  float lam = 1.f / (1.f + __expf(-lamw[0]));
  float T = temp[0];
  float oml = 1.f - lam;
  #pragma unroll
  for (int ti = 0; ti < 4; ti++) {
    int gi0 = by * 128 + wr + ti * 16 + quad * 4;
    float xi[4], yi[4], sqi[4];
    #pragma unroll
    for (int r = 0; r < 4; r++) {
      int gi = gi0 + r;
      xi[r] = pos[2 * gi]; yi[r] = pos[2 * gi + 1]; sqi[r] = sqf[gi];
    }
    #pragma unroll
    for (int tj = 0; tj < 4; tj++) {
      int gj = bx * 128 + wc + tj * 16 + m;
      float xj = pos[2 * gj], yj = pos[2 * gj + 1], sj = sqf[gj];
      f32x4 c = acc[ti][tj];
      #pragma unroll
      for (int r = 0; r < 4; r++) {
        float d2 = fmaxf(sqi[r] + sj - 2.f * (xi[r] * xj + yi[r] * yj), 0.f);
        float sp = __expf(-d2 * (1.f / 5000.f));
        float u = lam * c[r] + oml * sp;
        out[(size_t)(gi0 + r) * N + gj] = 1.f / (1.f + __expf(-u * T));
      }
    }
  }
}

// ---------------------------------------------------------------------------
// K3: per-row exact top-20 under emulated-numpy-fp32 arithmetic.
// Histogram threshold (unchanged) -> candidates -> NEW: cooperative staged
// recompute (coalesced loads, parallel div at staging, 64 lane-parallel
// sequential-FMA chains in frozen k-order) -> wave-parallel selection ->
// masked write. Emulated VALUE arithmetic is bit-identical to R2/R3.
// ---------------------------------------------------------------------------
__global__ __launch_bounds__(256) void topk_kernel(
    const float* __restrict__ feat, const float* __restrict__ pos,
    const float* __restrict__ normf, const float* __restrict__ sqf,
    const float* __restrict__ lamw, const float* __restrict__ temp,
    float* __restrict__ out) {
  __shared__ float vals[N];          // 32 KB; reused as T[128][64] in recompute
  __shared__ float ai[D];
  __shared__ int   hist[1024];
  __shared__ int   S[256];
  __shared__ int   thrBin;
  __shared__ int   candIdx[CAND_CAP];
  __shared__ float candV[CAND_CAP];
  __shared__ int   selIdx[KSEL];
  __shared__ float selVal[KSEL];
  __shared__ int   cnt;

  int row = blockIdx.x, t = threadIdx.x;
  float* orow = out + (size_t)row * N;
  const float* fi = feat + (size_t)row * D;
  float n_i = normf[row];

  for (int j = 4 * t; j < N; j += 1024)
    *(float4*)&vals[j] = *(const float4*)&orow[j];
  for (int k = t; k < D; k += 256) ai[k] = fi[k] / n_i;  // correctly-rounded = np
  #pragma unroll
  for (int b = 0; b < 4; b++) hist[t + 256 * b] = 0;
  if (t == 0) { thrBin = 0; cnt = 0; }
  __syncthreads();

  for (int j = t; j < N; j += 256) {
    int bin = (int)(vals[j] * 1024.f);
    bin = max(0, min(1023, bin));
    atomicAdd(&hist[bin], 1);
  }
  __syncthreads();

  S[t] = hist[4 * t] + hist[4 * t + 1] + hist[4 * t + 2] + hist[4 * t + 3];
  __syncthreads();
  for (int st = 1; st < 256; st <<= 1) {
    int add = (t + st < 256) ? S[t + st] : 0;
    __syncthreads();
    S[t] += add;
    __syncthreads();
  }
  {
    int tail = (t < 255) ? S[t + 1] : 0;
    int h0 = hist[4 * t], h1 = hist[4 * t + 1], h2 = hist[4 * t + 2], h3 = hist[4 * t + 3];
    int g3 = tail + h3;
    int g2 = g3 + h2;
    int g1 = g2 + h1;
    int g0 = g1 + h0;
    int best = -1;
    if      (g3 >= KSEL) best = 4 * t + 3;
    else if (g2 >= KSEL) best = 4 * t + 2;
    else if (g1 >= KSEL) best = 4 * t + 1;
    else if (g0 >= KSEL) best = 4 * t;
    if (best >= 0) atomicMax(&thrBin, best);
  }
  __syncthreads();

  float thr = (float)thrBin * (1.0f / 1024.f) - WINDOW;
  for (int j = t; j < N; j += 256) {
    if (vals[j] >= thr) {
      int p = atomicAdd(&cnt, 1);
      if (p < CAND_CAP) candIdx[p] = j;
    }
  }
  __syncthreads();
  int ncand = min(cnt, CAND_CAP);

  // --- staged np-exact recompute, 64 candidates per group ---
  float lamf;
  { float e = (float)exp(-(double)lamw[0]); lamf = 1.0f / __fadd_rn(1.0f, e); }
  float omlf = __fadd_rn(1.0f, -lamf);
  float Tf = temp[0];
  float sq_i = sqf[row];
  float xi = pos[2 * row], yi = pos[2 * row + 1];
  float* Tm = vals;   // filter values no longer needed
  int c4 = t >> 2, sub = t & 3;

  for (int g = 0; g < ncand; g += 64) {
    int sidx = g + c4;
    int sj = candIdx[(sidx < ncand) ? sidx : 0];
    const float* fj = feat + (size_t)sj * D + sub * 32;
    float n_j = normf[sj];
    float accv = 0.0f;
    int myIdx = g + t;   // chain candidate for lanes t<64
    for (int kk = 0; kk < D; kk += 128) {
      __syncthreads();   // previous chunk's chains done before overwrite
      #pragma unroll
      for (int q = 0; q < 8; q++) {
        float4 v = *(const float4*)(fj + kk + q * 4);
        int kl = sub * 32 + q * 4;
        Tm[(kl + 0) * 64 + c4] = v.x / n_j;   // correctly-rounded div = np
        Tm[(kl + 1) * 64 + c4] = v.y / n_j;
        Tm[(kl + 2) * 64 + c4] = v.z / n_j;
        Tm[(kl + 3) * 64 + c4] = v.w / n_j;
      }
      __syncthreads();
      if (t < 64) {
        for (int kl = 0; kl < 128; kl++)
          accv = __fmaf_rn(ai[kk + kl], Tm[kl * 64 + t], accv);  // frozen order
      }
    }
    if (t < 64 && myIdx < ncand) {
      int j = candIdx[myIdx];
      float xj = pos[2 * j], yj = pos[2 * j + 1];
      float dot2 = __fmaf_rn(yi, yj, __fmul_rn(xi, xj));
      float Ssum = __fadd_rn(sq_i, sqf[j]);
      float d2 = fmaxf(__fadd_rn(Ssum, -__fmul_rn(2.0f, dot2)), 0.0f);
      float arg = (-d2) / 5000.0f;
      float sp = (float)exp((double)arg);
      float u = __fmul_rn(__fadd_rn(__fmul_rn(lamf, accv), __fmul_rn(omlf, sp)), Tf);
      float e = (float)exp(-(double)u);
      candV[myIdx] = 1.0f / __fadd_rn(1.0f, e);
    }
  }
  __syncthreads();

  // --- wave-parallel selection: value desc, column asc (lax.top_k ties) ---
  for (int s = 0; s < KSEL; s++) {
    if (t < 64) {
      float bu = -1.0f; int bj = N, bs = 0;
      for (int c = t; c < ncand; c += 64) {
        float v = candV[c]; int j = candIdx[c];
        if (v > bu || (v == bu && j < bj)) { bu = v; bj = j; bs = c; }
      }
      #pragma unroll
      for (int off = 32; off > 0; off >>= 1) {
        float ov = __shfl_down(bu, off, 64);
        int   oj = __shfl_down(bj, off, 64);
        int   os = __shfl_down(bs, off, 64);
        if (ov > bu || (ov == bu && oj < bj)) { bu = ov; bj = oj; bs = os; }
      }
      if (t == 0) { selIdx[s] = bj; selVal[s] = bu; candV[bs] = -1.0f; }
    }
    __syncthreads();
  }

  // --- masked write via LDS, float4 streams ---
  float4 z4 = {0.f, 0.f, 0.f, 0.f};
  for (int j = 4 * t; j < N; j += 1024) *(float4*)&vals[j] = z4;
  __syncthreads();
  if (t < KSEL) vals[selIdx[t]] = selVal[t];
  __syncthreads();
  for (int j = 4 * t; j < N; j += 1024)
    *(float4*)&orow[j] = *(const float4*)&vals[j];
}

extern "C" void kernel_launch(void* const* d_in, const int* in_sizes, int n_in,
                              void* d_out, int out_size, void* d_ws, size_t ws_size,
                              hipStream_t stream) {
  const float* feat = (const float*)d_in[0];
  const float* pos  = (const float*)d_in[1];
  const float* lamw = (const float*)d_in[2];
  const float* temp = (const float*)d_in[3];
  float* out = (float*)d_out;
  float* normf = (float*)d_ws;                       // N floats
  float* sqf   = normf + N;                          // N floats
  unsigned short* fnbf = (unsigned short*)(sqf + N); // N*D bf16 (8 MB)
  size_t need = (size_t)2 * N * sizeof(float) + (size_t)N * D * 2;

  prep_kernel<<<N / 256, 256, 0, stream>>>(feat, pos, lamw, normf, sqf, out);
  dim3 g(N / 128, N / 128);
  if (ws_size >= need) {
    fnorm_kernel<<<(N * D) / 1024, 256, 0, stream>>>(feat, normf, fnbf);
    adj_fast<<<g, 256, 0, stream>>>(fnbf, pos, sqf, lamw, temp, out);
  } else {
    adj_slow<<<g, 256, 0, stream>>>(feat, pos, normf, sqf, lamw, temp, out);
  }
  topk_kernel<<<N, 256, 0, stream>>>(feat, pos, normf, sqf, lamw, temp, out);
}

// Round 5
// 768.505 us; speedup vs baseline: 3.0814x; 1.1847x over previous
//
#include <hip/hip_runtime.h>
#include <math.h>

#define N 8192
#define D 512
#define KSEL 20
#define CAND_CAP 512
#define WINDOW 6e-3f

typedef __attribute__((ext_vector_type(8))) short short8;
typedef __attribute__((ext_vector_type(4))) float f32x4;

__device__ __forceinline__ unsigned short f2bf(float x) {
  unsigned int u = __float_as_uint(x);
  unsigned int r = u + 0x7FFFu + ((u >> 16) & 1u);   // RNE to bf16
  return (unsigned short)(r >> 16);
}

__device__ __forceinline__ void gld16(const unsigned short* g, unsigned short* l) {
  __builtin_amdgcn_global_load_lds(
      (const __attribute__((address_space(1))) unsigned int*)g,
      (__attribute__((address_space(3))) unsigned int*)l, 16, 0, 0);
}

// ---------------------------------------------------------------------------
// K1: emulate numpy float32 prep per row (FROZEN — verified bit-exact).
// ---------------------------------------------------------------------------
__global__ __launch_bounds__(256) void prep_kernel(
    const float* __restrict__ feat, const float* __restrict__ pos,
    const float* __restrict__ lamw,
    float* __restrict__ normf, float* __restrict__ sqf,
    float* __restrict__ out) {
  int row = blockIdx.x * 256 + threadIdx.x;
  if (row >= N) return;
  const float* f = feat + (size_t)row * D;
  float part[4];
  #pragma unroll
  for (int b = 0; b < 4; b++) {
    const float* a = f + b * 128;
    float r[8];
    #pragma unroll
    for (int j = 0; j < 8; j++) r[j] = __fmul_rn(a[j], a[j]);
    for (int i = 8; i < 128; i += 8) {
      #pragma unroll
      for (int j = 0; j < 8; j++)
        r[j] = __fadd_rn(r[j], __fmul_rn(a[i + j], a[i + j]));
    }
    part[b] = __fadd_rn(__fadd_rn(__fadd_rn(r[0], r[1]), __fadd_rn(r[2], r[3])),
                        __fadd_rn(__fadd_rn(r[4], r[5]), __fadd_rn(r[6], r[7])));
  }
  float s = __fadd_rn(__fadd_rn(part[0], part[1]), __fadd_rn(part[2], part[3]));
  float nrm = fmaxf(__fsqrt_rn(s), 1e-12f);
  normf[row] = nrm;
  float x = pos[2 * row], y = pos[2 * row + 1];
  sqf[row] = __fadd_rn(__fmul_rn(x, x), __fmul_rn(y, y));
  if (row == 0) {
    float e = (float)exp(-(double)lamw[0]);
    out[(size_t)N * N] = 1.0f / __fadd_rn(1.0f, e);
  }
}

// ---------------------------------------------------------------------------
// K1b: bf16 normalized-feature matrix (filter precision only).
// ---------------------------------------------------------------------------
__global__ __launch_bounds__(256) void fnorm_kernel(
    const float* __restrict__ feat, const float* __restrict__ normf,
    unsigned short* __restrict__ fb) {
  int i0 = (blockIdx.x * 256 + threadIdx.x) * 4;
  float n = normf[i0 >> 9];
  float4 v = *(const float4*)(feat + i0);
  unsigned int lo = (unsigned int)f2bf(v.x / n) | ((unsigned int)f2bf(v.y / n) << 16);
  unsigned int hi = (unsigned int)f2bf(v.z / n) | ((unsigned int)f2bf(v.w / n) << 16);
  uint2 o; o.x = lo; o.y = hi;
  *(uint2*)(fb + i0) = o;
}

// ---------------------------------------------------------------------------
// K2: bf16 MFMA filter GEMM. Output: sigma values packed as bf16 PAIRS into
// the FIRST N/2 floats of each row's own out region (row-local; topk for row
// r reads only row r's region before overwriting it -> no cross-row hazard).
// ---------------------------------------------------------------------------
__global__ __launch_bounds__(256) void adj_fast(
    const unsigned short* __restrict__ G,
    const float* __restrict__ pos, const float* __restrict__ sqf,
    const float* __restrict__ lamw, const float* __restrict__ temp,
    unsigned int* __restrict__ out_u) {
  __shared__ __align__(16) unsigned short As[128 * 64];
  __shared__ __align__(16) unsigned short Bs[128 * 64];
  int bx = blockIdx.x, by = blockIdx.y;
  int tid = threadIdx.x;
  int wave = tid >> 6, lane = tid & 63;
  int wr = (wave >> 1) * 64, wc = (wave & 1) * 64;
  int m = lane & 15, quad = lane >> 4;

  f32x4 acc[4][4];
  #pragma unroll
  for (int i = 0; i < 4; i++)
    #pragma unroll
    for (int j = 0; j < 4; j++) acc[i][j] = (f32x4){0.f, 0.f, 0.f, 0.f};

  for (int kt = 0; kt < D / 64; kt++) {
    #pragma unroll
    for (int i = 0; i < 4; i++) {
      int f = i * 256 + tid;
      int r = f >> 3, c = f & 7;
      int cs = (c + r) & 7;
      size_t goff = (size_t)r * D + kt * 64 + cs * 8;
      gld16(G + (size_t)(by * 128) * D + goff, &As[f * 8]);
      gld16(G + (size_t)(bx * 128) * D + goff, &Bs[f * 8]);
    }
    __syncthreads();
    #pragma unroll
    for (int h = 0; h < 2; h++) {
      short8 fa[4], fb[4];
      #pragma unroll
      for (int ti = 0; ti < 4; ti++) {
        int row = wr + ti * 16 + m;
        int cc = ((h * 4 + quad) - row) & 7;
        fa[ti] = *(const short8*)&As[row * 64 + cc * 8];
      }
      #pragma unroll
      for (int tj = 0; tj < 4; tj++) {
        int row = wc + tj * 16 + m;
        int cc = ((h * 4 + quad) - row) & 7;
        fb[tj] = *(const short8*)&Bs[row * 64 + cc * 8];
      }
      #pragma unroll
      for (int ti = 0; ti < 4; ti++)
        #pragma unroll
        for (int tj = 0; tj < 4; tj++)
          acc[ti][tj] = __builtin_amdgcn_mfma_f32_16x16x32_bf16(
              fa[ti], fb[tj], acc[ti][tj], 0, 0, 0);
    }
    __syncthreads();
  }

  float lam = 1.f / (1.f + __expf(-lamw[0]));
  float T = temp[0];
  float oml = 1.f - lam;
  #pragma unroll
  for (int ti = 0; ti < 4; ti++) {
    int gi0 = by * 128 + wr + ti * 16 + quad * 4;
    float xi[4], yi[4], sqi[4];
    #pragma unroll
    for (int r = 0; r < 4; r++) {
      int gi = gi0 + r;
      xi[r] = pos[2 * gi]; yi[r] = pos[2 * gi + 1]; sqi[r] = sqf[gi];
    }
    #pragma unroll
    for (int tj = 0; tj < 4; tj++) {
      int gj = bx * 128 + wc + tj * 16 + m;
      float xj = pos[2 * gj], yj = pos[2 * gj + 1], sj = sqf[gj];
      f32x4 c = acc[ti][tj];
      #pragma unroll
      for (int r = 0; r < 4; r++) {
        float d2 = fmaxf(sqi[r] + sj - 2.f * (xi[r] * xj + yi[r] * yj), 0.f);
        float sp = __expf(-d2 * (1.f / 5000.f));
        float u = lam * c[r] + oml * sp;
        float v = 1.f / (1.f + __expf(-u * T));
        float pv = __shfl_xor(v, 1, 64);          // partner col gj^1
        if (!(lane & 1)) {
          unsigned int pk = (unsigned int)f2bf(v) | ((unsigned int)f2bf(pv) << 16);
          out_u[(size_t)(gi0 + r) * N + (gj >> 1)] = pk;
        }
      }
    }
  }
}

// ---------------------------------------------------------------------------
// K2 fallback (ws too small for fnorm): R3-style kernel, same bf16-pair output.
// ---------------------------------------------------------------------------
__global__ __launch_bounds__(256) void adj_slow(
    const float* __restrict__ feat, const float* __restrict__ pos,
    const float* __restrict__ normf, const float* __restrict__ sqf,
    const float* __restrict__ lamw, const float* __restrict__ temp,
    unsigned int* __restrict__ out_u) {
  __shared__ unsigned short As[128][40];
  __shared__ unsigned short Bs[128][40];
  int bx = blockIdx.x, by = blockIdx.y;
  int tid = threadIdx.x;
  int wave = tid >> 6, lane = tid & 63;
  int wr = (wave >> 1) * 64, wc = (wave & 1) * 64;
  int m = lane & 15, quad = lane >> 4;
  int sr = tid >> 1;
  int k0 = (tid & 1) * 16;
  int arow = by * 128 + sr, brow = bx * 128 + sr;
  float ia = 1.0f / normf[arow], ib = 1.0f / normf[brow];
  const float* af = feat + (size_t)arow * D + k0;
  const float* bf = feat + (size_t)brow * D + k0;

  f32x4 acc[4][4];
  #pragma unroll
  for (int i = 0; i < 4; i++)
    #pragma unroll
    for (int j = 0; j < 4; j++) acc[i][j] = (f32x4){0.f, 0.f, 0.f, 0.f};

  for (int kt = 0; kt < D / 32; kt++) {
    const float* pA = af + kt * 32;
    const float* pB = bf + kt * 32;
    float4 a0 = *(const float4*)(pA);     float4 a1 = *(const float4*)(pA + 4);
    float4 a2 = *(const float4*)(pA + 8); float4 a3 = *(const float4*)(pA + 12);
    float4 b0 = *(const float4*)(pB);     float4 b1 = *(const float4*)(pB + 4);
    float4 b2 = *(const float4*)(pB + 8); float4 b3 = *(const float4*)(pB + 12);
    short8 wa0, wa1, wb0, wb1;
    wa0[0]=f2bf(a0.x*ia); wa0[1]=f2bf(a0.y*ia); wa0[2]=f2bf(a0.z*ia); wa0[3]=f2bf(a0.w*ia);
    wa0[4]=f2bf(a1.x*ia); wa0[5]=f2bf(a1.y*ia); wa0[6]=f2bf(a1.z*ia); wa0[7]=f2bf(a1.w*ia);
    wa1[0]=f2bf(a2.x*ia); wa1[1]=f2bf(a2.y*ia); wa1[2]=f2bf(a2.z*ia); wa1[3]=f2bf(a2.w*ia);
    wa1[4]=f2bf(a3.x*ia); wa1[5]=f2bf(a3.y*ia); wa1[6]=f2bf(a3.z*ia); wa1[7]=f2bf(a3.w*ia);
    wb0[0]=f2bf(b0.x*ib); wb0[1]=f2bf(b0.y*ib); wb0[2]=f2bf(b0.z*ib); wb0[3]=f2bf(b0.w*ib);
    wb0[4]=f2bf(b1.x*ib); wb0[5]=f2bf(b1.y*ib); wb0[6]=f2bf(b1.z*ib); wb0[7]=f2bf(b1.w*ib);
    wb1[0]=f2bf(b2.x*ib); wb1[1]=f2bf(b2.y*ib); wb1[2]=f2bf(b2.z*ib); wb1[3]=f2bf(b2.w*ib);
    wb1[4]=f2bf(b3.x*ib); wb1[5]=f2bf(b3.y*ib); wb1[6]=f2bf(b3.z*ib); wb1[7]=f2bf(b3.w*ib);
    *(short8*)&As[sr][k0]     = wa0;
    *(short8*)&As[sr][k0 + 8] = wa1;
    *(short8*)&Bs[sr][k0]     = wb0;
    *(short8*)&Bs[sr][k0 + 8] = wb1;
    __syncthreads();
    short8 fa[4], fb[4];
    #pragma unroll
    for (int ti = 0; ti < 4; ti++)
      fa[ti] = *(const short8*)&As[wr + ti * 16 + m][quad * 8];
    #pragma unroll
    for (int tj = 0; tj < 4; tj++)
      fb[tj] = *(const short8*)&Bs[wc + tj * 16 + m][quad * 8];
    #pragma unroll
    for (int ti = 0; ti < 4; ti++)
      #pragma unroll
      for (int tj = 0; tj < 4; tj++)
        acc[ti][tj] = __builtin_amdgcn_mfma_f32_16x16x32_bf16(
            fa[ti], fb[tj], acc[ti][tj], 0, 0, 0);
    __syncthreads();
  }

  float lam = 1.f / (1.f + __expf(-lamw[0]));
  float T = temp[0];
  float oml = 1.f - lam;
  #pragma unroll
  for (int ti = 0; ti < 4; ti++) {
    int gi0 = by * 128 + wr + ti * 16 + quad * 4;
    float xi[4], yi[4], sqi[4];
    #pragma unroll
    for (int r = 0; r < 4; r++) {
      int gi = gi0 + r;
      xi[r] = pos[2 * gi]; yi[r] = pos[2 * gi + 1]; sqi[r] = sqf[gi];
    }
    #pragma unroll
    for (int tj = 0; tj < 4; tj++) {
      int gj = bx * 128 + wc + tj * 16 + m;
      float xj = pos[2 * gj], yj = pos[2 * gj + 1], sj = sqf[gj];
      f32x4 c = acc[ti][tj];
      #pragma unroll
      for (int r = 0; r < 4; r++) {
        float d2 = fmaxf(sqi[r] + sj - 2.f * (xi[r] * xj + yi[r] * yj), 0.f);
        float sp = __expf(-d2 * (1.f / 5000.f));
        float u = lam * c[r] + oml * sp;
        float v = 1.f / (1.f + __expf(-u * T));
        float pv = __shfl_xor(v, 1, 64);
        if (!(lane & 1)) {
          unsigned int pk = (unsigned int)f2bf(v) | ((unsigned int)f2bf(pv) << 16);
          out_u[(size_t)(gi0 + r) * N + (gj >> 1)] = pk;
        }
      }
    }
  }
}

// ---------------------------------------------------------------------------
// K3: per-row exact top-20 under emulated-numpy-fp32 arithmetic.
// Row filter (bf16) held in 32 VGPRs/thread; 14-iter binary search on
// count_ge (no atomics, no histogram); candidate sweep from regs; staged
// np-exact recompute (FROZEN arithmetic) with 2-way-free LDS swizzle;
// wave-parallel selection; streamed masked write.
// ---------------------------------------------------------------------------
__global__ __launch_bounds__(256, 4) void topk_kernel(
    const float* __restrict__ feat, const float* __restrict__ pos,
    const float* __restrict__ normf, const float* __restrict__ sqf,
    const float* __restrict__ lamw, const float* __restrict__ temp,
    float* __restrict__ out) {
  __shared__ float Tm[N];            // 32 KB: staging + final scatter
  __shared__ float ai[D];
  __shared__ int   redi[4];
  __shared__ int   candIdx[CAND_CAP];
  __shared__ float candV[CAND_CAP];
  __shared__ int   selIdx[KSEL];
  __shared__ float selVal[KSEL];
  __shared__ int   cnt;

  int row = blockIdx.x, t = threadIdx.x;
  int lane = t & 63, wid = t >> 6;
  float* orow = out + (size_t)row * N;
  const unsigned int* ou = (const unsigned int*)orow;
  const float* fi = feat + (size_t)row * D;
  float n_i = normf[row];

  // row filter -> 32 regs (bf16 pairs). rv[2q+e] => col j = 2*(t+256q)+e
  float rv[32];
  #pragma unroll
  for (int q = 0; q < 16; q++) {
    unsigned int u = ou[t + 256 * q];
    rv[2 * q]     = __uint_as_float(u << 16);
    rv[2 * q + 1] = __uint_as_float(u & 0xFFFF0000u);
  }
  for (int k = t; k < D; k += 256) ai[k] = fi[k] / n_i;  // correctly-rounded = np
  if (t == 0) cnt = 0;
  __syncthreads();

  // --- binary search for threshold: count_ge(lo) >= 20 > count_ge(hi) ---
  float lo = 0.f, hi = 1.f;
  for (int it = 0; it < 14; it++) {
    float mid = 0.5f * (lo + hi);
    int c = 0;
    #pragma unroll
    for (int q = 0; q < 32; q++) c += (rv[q] >= mid) ? 1 : 0;
    #pragma unroll
    for (int off = 32; off > 0; off >>= 1) c += __shfl_down(c, off, 64);
    __syncthreads();                       // prior iter's redi reads done
    if (lane == 0) redi[wid] = c;
    __syncthreads();
    int tot = redi[0] + redi[1] + redi[2] + redi[3];
    if (tot >= KSEL) lo = mid; else hi = mid;
  }

  // --- candidate sweep from regs ---
  float thr = lo - WINDOW;
  #pragma unroll
  for (int q = 0; q < 32; q++) {
    if (rv[q] >= thr) {
      int p = atomicAdd(&cnt, 1);
      if (p < CAND_CAP) candIdx[p] = 2 * (t + 256 * (q >> 1)) + (q & 1);
    }
  }
  __syncthreads();
  int ncand = min(cnt, CAND_CAP);

  // --- staged np-exact recompute (FROZEN value arithmetic) ---
  float lamf;
  { float e = (float)exp(-(double)lamw[0]); lamf = 1.0f / __fadd_rn(1.0f, e); }
  float omlf = __fadd_rn(1.0f, -lamf);
  float Tf = temp[0];
  float sq_i = sqf[row];
  float xi = pos[2 * row], yi = pos[2 * row + 1];
  int c4 = t >> 2, sub = t & 3;

  for (int g = 0; g < ncand; g += 64) {
    int sidx = g + c4;
    int sj = candIdx[(sidx < ncand) ? sidx : 0];
    const float* fj = feat + (size_t)sj * D + sub * 32;
    float n_j = normf[sj];
    float accv = 0.0f;
    int myIdx = g + t;
    for (int kk = 0; kk < D; kk += 128) {
      __syncthreads();   // previous chunk's chains done before overwrite
      // swizzled store: slot s = (c4 + sub*16) & 63  -> 2-way (free) banks
      int sbase = (c4 + sub * 16) & 63;
      #pragma unroll
      for (int q = 0; q < 8; q++) {
        float4 v = *(const float4*)(fj + kk + q * 4);
        int kl = sub * 32 + q * 4;
        Tm[(kl + 0) * 64 + sbase] = v.x / n_j;   // correctly-rounded div = np
        Tm[(kl + 1) * 64 + sbase] = v.y / n_j;
        Tm[(kl + 2) * 64 + sbase] = v.z / n_j;
        Tm[(kl + 3) * 64 + sbase] = v.w / n_j;
      }
      __syncthreads();
      if (t < 64) {
        for (int kl = 0; kl < 128; kl++) {
          int s = (t + ((kl >> 5) << 4)) & 63;
          accv = __fmaf_rn(ai[kk + kl], Tm[kl * 64 + s], accv);  // frozen order
        }
      }
    }
    if (t < 64 && myIdx < ncand) {
      int j = candIdx[myIdx];
      float xj = pos[2 * j], yj = pos[2 * j + 1];
      float dot2 = __fmaf_rn(yi, yj, __fmul_rn(xi, xj));
      float Ssum = __fadd_rn(sq_i, sqf[j]);
      float d2 = fmaxf(__fadd_rn(Ssum, -__fmul_rn(2.0f, dot2)), 0.0f);
      float arg = (-d2) / 5000.0f;
      float sp = (float)exp((double)arg);
      float u = __fmul_rn(__fadd_rn(__fmul_rn(lamf, accv), __fmul_rn(omlf, sp)), Tf);
      float e = (float)exp(-(double)u);
      candV[myIdx] = 1.0f / __fadd_rn(1.0f, e);
    }
  }
  __syncthreads();

  // --- wave-parallel selection: value desc, index asc (lax.top_k ties) ---
  for (int s = 0; s < KSEL; s++) {
    if (t < 64) {
      float bu = -1.0f; int bj = N, bs = 0;
      for (int c = t; c < ncand; c += 64) {
        float v = candV[c]; int j = candIdx[c];
        if (v > bu || (v == bu && j < bj)) { bu = v; bj = j; bs = c; }
      }
      #pragma unroll
      for (int off = 32; off > 0; off >>= 1) {
        float ov = __shfl_down(bu, off, 64);
        int   oj = __shfl_down(bj, off, 64);
        int   os = __shfl_down(bs, off, 64);
        if (ov > bu || (ov == bu && oj < bj)) { bu = ov; bj = oj; bs = os; }
      }
      if (t == 0) { selIdx[s] = bj; selVal[s] = bu; candV[bs] = -1.0f; }
    }
    __syncthreads();
  }

  // --- masked write via LDS scatter, float4 streams ---
  float4 z4 = {0.f, 0.f, 0.f, 0.f};
  for (int j = 4 * t; j < N; j += 1024) *(float4*)&Tm[j] = z4;
  __syncthreads();
  if (t < KSEL) Tm[selIdx[t]] = selVal[t];
  __syncthreads();
  for (int j = 4 * t; j < N; j += 1024)
    *(float4*)&orow[j] = *(const float4*)&Tm[j];
}

extern "C" void kernel_launch(void* const* d_in, const int* in_sizes, int n_in,
                              void* d_out, int out_size, void* d_ws, size_t ws_size,
                              hipStream_t stream) {
  const float* feat = (const float*)d_in[0];
  const float* pos  = (const float*)d_in[1];
  const float* lamw = (const float*)d_in[2];
  const float* temp = (const float*)d_in[3];
  float* out = (float*)d_out;
  unsigned int* out_u = (unsigned int*)d_out;
  float* normf = (float*)d_ws;                       // N floats
  float* sqf   = normf + N;                          // N floats
  unsigned short* fnbf = (unsigned short*)(sqf + N); // N*D bf16 (8 MB)
  size_t need = (size_t)2 * N * sizeof(float) + (size_t)N * D * 2;

  prep_kernel<<<N / 256, 256, 0, stream>>>(feat, pos, lamw, normf, sqf, out);
  dim3 g(N / 128, N / 128);
  if (ws_size >= need) {
    fnorm_kernel<<<(N * D) / 1024, 256, 0, stream>>>(feat, normf, fnbf);
    adj_fast<<<g, 256, 0, stream>>>(fnbf, pos, sqf, lamw, temp, out_u);
  } else {
    adj_slow<<<g, 256, 0, stream>>>(feat, pos, normf, sqf, lamw, temp, out_u);
  }
  topk_kernel<<<N, 256, 0, stream>>>(feat, pos, normf, sqf, lamw, temp, out);
}

// Round 6
// 743.389 us; speedup vs baseline: 3.1856x; 1.0338x over previous
//
#include <hip/hip_runtime.h>
#include <hip/hip_fp16.h>
#include <math.h>

#define N 8192
#define D 512
#define KSEL 20
#define CAND_CAP 512
#define WINDOW 2.5e-3f
// out row = 8192 dwords. [0,4096): filter fp16 pairs. [4096,4608): fnorm32.
// [4608,4864): fnorm bf16 pairs. [4864,4904): sel idx/val (20+20).
#define ROWU 8192
#define FN32_OFF 4096
#define FBF_OFF_US 9216   // ushort offset of bf16 section (4608 dwords * 2)
#define SELI_OFF 4864
#define SELV_OFF 4884

typedef __attribute__((ext_vector_type(8))) short short8;
typedef __attribute__((ext_vector_type(4))) float f32x4;

__device__ __forceinline__ unsigned short f2bf(float x) {
  unsigned int u = __float_as_uint(x);
  unsigned int r = u + 0x7FFFu + ((u >> 16) & 1u);
  return (unsigned short)(r >> 16);
}

__device__ __forceinline__ unsigned int packh2(float a, float b) {
  return (unsigned int)__half_as_ushort(__float2half(a)) |
         ((unsigned int)__half_as_ushort(__float2half(b)) << 16);
}

__device__ __forceinline__ void gld16(const unsigned short* g, unsigned short* l) {
  __builtin_amdgcn_global_load_lds(
      (const __attribute__((address_space(1))) unsigned int*)g,
      (__attribute__((address_space(3))) unsigned int*)l, 16, 0, 0);
}

// ---------------------------------------------------------------------------
// K1: np-exact fp32 prep (FROZEN): pairwise-sum norm, sq pos, lam scalar.
// ---------------------------------------------------------------------------
__global__ __launch_bounds__(256) void prep_kernel(
    const float* __restrict__ feat, const float* __restrict__ pos,
    const float* __restrict__ lamw,
    float* __restrict__ normf, float* __restrict__ sqf,
    float* __restrict__ out) {
  int row = blockIdx.x * 256 + threadIdx.x;
  if (row >= N) return;
  const float* f = feat + (size_t)row * D;
  float part[4];
  #pragma unroll
  for (int b = 0; b < 4; b++) {
    const float* a = f + b * 128;
    float r[8];
    #pragma unroll
    for (int j = 0; j < 8; j++) r[j] = __fmul_rn(a[j], a[j]);
    for (int i = 8; i < 128; i += 8) {
      #pragma unroll
      for (int j = 0; j < 8; j++)
        r[j] = __fadd_rn(r[j], __fmul_rn(a[i + j], a[i + j]));
    }
    part[b] = __fadd_rn(__fadd_rn(__fadd_rn(r[0], r[1]), __fadd_rn(r[2], r[3])),
                        __fadd_rn(__fadd_rn(r[4], r[5]), __fadd_rn(r[6], r[7])));
  }
  float s = __fadd_rn(__fadd_rn(part[0], part[1]), __fadd_rn(part[2], part[3]));
  float nrm = fmaxf(__fsqrt_rn(s), 1e-12f);
  normf[row] = nrm;
  float x = pos[2 * row], y = pos[2 * row + 1];
  sqf[row] = __fadd_rn(__fmul_rn(x, x), __fmul_rn(y, y));
  if (row == 0) {
    float e = (float)exp(-(double)lamw[0]);
    out[(size_t)N * N] = 1.0f / __fadd_rn(1.0f, e);
  }
}

// ---------------------------------------------------------------------------
// K1b: per-row np-exact normalized features: fp32 (for recompute, bit-exact
// correctly-rounded div) and bf16 (for MFMA filter), stored in each row's
// second half of out.
// ---------------------------------------------------------------------------
__global__ __launch_bounds__(256) void fnorm_kernel(
    const float* __restrict__ feat, const float* __restrict__ normf,
    unsigned int* __restrict__ out_u) {
  int i0 = (blockIdx.x * 256 + threadIdx.x) * 4;
  int row = i0 >> 9, k = i0 & (D - 1);
  float n = normf[row];
  float4 v = *(const float4*)(feat + i0);
  float4 q;
  q.x = v.x / n; q.y = v.y / n; q.z = v.z / n; q.w = v.w / n;
  float* f32dst = (float*)(out_u + (size_t)row * ROWU + FN32_OFF);
  *(float4*)(f32dst + k) = q;
  unsigned int lo = (unsigned int)f2bf(q.x) | ((unsigned int)f2bf(q.y) << 16);
  unsigned int hi = (unsigned int)f2bf(q.z) | ((unsigned int)f2bf(q.w) << 16);
  uint2 o; o.x = lo; o.y = hi;
  *(uint2*)(out_u + (size_t)row * ROWU + (FBF_OFF_US >> 1) + (k >> 1)) = o;
}

// ---------------------------------------------------------------------------
// K2: symmetric bf16-MFMA filter. Triangular grid (bx>=by, 2080 blocks).
// Computes pre-sigmoid s = (lam*sim + (1-lam)*spatial)*T (monotone under
// sigmoid -> same ranking), writes fp16 pairs into out rows (first halves):
// tile rows (by-strip) directly + LDS-transposed mirror into bx-strip rows.
// ---------------------------------------------------------------------------
__global__ __launch_bounds__(256) void adj_kernel(
    const float* __restrict__ pos, const float* __restrict__ sqf,
    const float* __restrict__ lamw, const float* __restrict__ temp,
    unsigned int* out_u) {
  __shared__ __align__(16) unsigned char smem[32768];
  unsigned short* As = (unsigned short*)smem;        // 128*64 ushort
  unsigned short* Bs = As + 8192;
  unsigned int* tileT = (unsigned int*)smem;         // union: 128*64 dwords
  const unsigned short* G = (const unsigned short*)out_u;

  int L = blockIdx.x;
  int by = (int)((129.0 - sqrt(129.0 * 129.0 - 8.0 * (double)L)) * 0.5);
  while (64 * (by + 1) - ((by + 1) * by) / 2 <= L) by++;
  while (64 * by - (by * (by - 1)) / 2 > L) by--;
  int bx = by + (L - (64 * by - (by * (by - 1)) / 2));

  int tid = threadIdx.x;
  int wave = tid >> 6, lane = tid & 63;
  int wr = (wave >> 1) * 64, wc = (wave & 1) * 64;
  int m = lane & 15, quad = lane >> 4;

  f32x4 acc[4][4];
  #pragma unroll
  for (int i = 0; i < 4; i++)
    #pragma unroll
    for (int j = 0; j < 4; j++) acc[i][j] = (f32x4){0.f, 0.f, 0.f, 0.f};

  for (int kt = 0; kt < D / 64; kt++) {
    #pragma unroll
    for (int i = 0; i < 4; i++) {
      int f = i * 256 + tid;
      int r = f >> 3, c = f & 7;
      int cs = (c + r) & 7;
      size_t koff = (size_t)FBF_OFF_US + kt * 64 + cs * 8;
      gld16(G + (size_t)(by * 128 + r) * (2 * ROWU) + koff, &As[f * 8]);
      gld16(G + (size_t)(bx * 128 + r) * (2 * ROWU) + koff, &Bs[f * 8]);
    }
    __syncthreads();
    #pragma unroll
    for (int h = 0; h < 2; h++) {
      short8 fa[4], fb[4];
      #pragma unroll
      for (int ti = 0; ti < 4; ti++) {
        int row = wr + ti * 16 + m;
        int cc = ((h * 4 + quad) - row) & 7;
        fa[ti] = *(const short8*)&As[row * 64 + cc * 8];
      }
      #pragma unroll
      for (int tj = 0; tj < 4; tj++) {
        int row = wc + tj * 16 + m;
        int cc = ((h * 4 + quad) - row) & 7;
        fb[tj] = *(const short8*)&Bs[row * 64 + cc * 8];
      }
      #pragma unroll
      for (int ti = 0; ti < 4; ti++)
        #pragma unroll
        for (int tj = 0; tj < 4; tj++)
          acc[ti][tj] = __builtin_amdgcn_mfma_f32_16x16x32_bf16(
              fa[ti], fb[tj], acc[ti][tj], 0, 0, 0);
    }
    __syncthreads();   // also fences As/Bs before tileT reuse below
  }

  float lam = 1.f / (1.f + __expf(-lamw[0]));
  float T = temp[0];
  float oml = 1.f - lam;
  bool offdiag = (bx != by);
  #pragma unroll
  for (int ti = 0; ti < 4; ti++) {
    int gi0 = by * 128 + wr + ti * 16 + quad * 4;
    float xi[4], yi[4], sqi[4];
    #pragma unroll
    for (int r = 0; r < 4; r++) {
      int gi = gi0 + r;
      xi[r] = pos[2 * gi]; yi[r] = pos[2 * gi + 1]; sqi[r] = sqf[gi];
    }
    #pragma unroll
    for (int tj = 0; tj < 4; tj++) {
      int gj = bx * 128 + wc + tj * 16 + m;
      float xj = pos[2 * gj], yj = pos[2 * gj + 1], sj = sqf[gj];
      f32x4 c = acc[ti][tj];
      float sv[4];
      #pragma unroll
      for (int r = 0; r < 4; r++) {
        float d2 = fmaxf(sqi[r] + sj - 2.f * (xi[r] * xj + yi[r] * yj), 0.f);
        float sp = __expf(-d2 * (1.f / 5000.f));
        sv[r] = (lam * c[r] + oml * sp) * T;   // pre-sigmoid score
      }
      #pragma unroll
      for (int r = 0; r < 4; r++) {
        float pv = __shfl_xor(sv[r], 1, 64);
        if (!(lane & 1))
          out_u[(size_t)(gi0 + r) * ROWU + (gj >> 1)] = packh2(sv[r], pv);
      }
      if (offdiag) {
        int colL = wc + tj * 16 + m;
        int p0 = (wr + ti * 16) / 2 + quad * 2;
        tileT[colL * 64 + (p0 ^ (colL & 31))]       = packh2(sv[0], sv[1]);
        tileT[colL * 64 + ((p0 + 1) ^ (colL & 31))] = packh2(sv[2], sv[3]);
      }
    }
  }
  if (offdiag) {
    __syncthreads();
    int p = tid & 63, c0 = tid >> 6;
    for (int it = 0; it < 32; it++) {
      int c = it * 4 + c0;
      unsigned int w = tileT[c * 64 + (p ^ (c & 31))];
      out_u[(size_t)(bx * 128 + c) * ROWU + (by * 64 + p)] = w;
    }
  }
}

// ---------------------------------------------------------------------------
// K3: per-row exact top-20. Filter (fp16 s-space) -> 32 regs -> 18-iter
// binary search for t20 -> candidates (W=2.5e-3 in s-space) -> staged
// np-exact recompute from precomputed fnorm32 (FROZEN fp32 arithmetic,
// no divs) -> wave-parallel selection -> sel list stored row-locally.
// ---------------------------------------------------------------------------
__global__ __launch_bounds__(256, 4) void topk_kernel(
    const float* __restrict__ pos, const float* __restrict__ sqf,
    const float* __restrict__ lamw, const float* __restrict__ temp,
    unsigned int* out_u) {
  __shared__ float Tm[N];            // 32 KB staging
  __shared__ float ai[D];
  __shared__ int   redi[4];
  __shared__ int   candIdx[CAND_CAP];
  __shared__ float candV[CAND_CAP];
  __shared__ int   selIdx[KSEL];
  __shared__ float selVal[KSEL];
  __shared__ int   cnt;

  int row = blockIdx.x, t = threadIdx.x;
  int lane = t & 63, wid = t >> 6;
  const unsigned int* ou = out_u + (size_t)row * ROWU;
  const float* fn32_i = (const float*)(ou + FN32_OFF);

  float rv[32];
  #pragma unroll
  for (int q = 0; q < 16; q++) {
    unsigned int u = ou[t + 256 * q];
    __half2 h2 = *reinterpret_cast<__half2*>(&u);
    rv[2 * q]     = __low2float(h2);
    rv[2 * q + 1] = __high2float(h2);
  }
  for (int k = t; k < D; k += 256) ai[k] = fn32_i[k];   // np-exact a_i
  if (t == 0) cnt = 0;
  __syncthreads();

  // --- binary search: lo <= s_t20, count_ge(lo) >= 20 ---
  float lo = -8.f, hi = 8.f;
  for (int it = 0; it < 18; it++) {
    float mid = 0.5f * (lo + hi);
    int c = 0;
    #pragma unroll
    for (int q = 0; q < 32; q++) c += (rv[q] >= mid) ? 1 : 0;
    #pragma unroll
    for (int off = 32; off > 0; off >>= 1) c += __shfl_down(c, off, 64);
    __syncthreads();
    if (lane == 0) redi[wid] = c;
    __syncthreads();
    int tot = redi[0] + redi[1] + redi[2] + redi[3];
    if (tot >= KSEL) lo = mid; else hi = mid;
  }

  float thr = lo - WINDOW;
  #pragma unroll
  for (int q = 0; q < 32; q++) {
    if (rv[q] >= thr) {
      int p = atomicAdd(&cnt, 1);
      if (p < CAND_CAP) candIdx[p] = 2 * (t + 256 * (q >> 1)) + (q & 1);
    }
  }
  __syncthreads();
  int ncand = min(cnt, CAND_CAP);

  // --- staged np-exact recompute (FROZEN value arithmetic, no divs) ---
  float lamf;
  { float e = (float)exp(-(double)lamw[0]); lamf = 1.0f / __fadd_rn(1.0f, e); }
  float omlf = __fadd_rn(1.0f, -lamf);
  float Tf = temp[0];
  float sq_i = sqf[row];
  float xi = pos[2 * row], yi = pos[2 * row + 1];
  int c4 = t >> 2, sub = t & 3;

  for (int g = 0; g < ncand; g += 64) {
    int sidx = g + c4;
    int sj = candIdx[(sidx < ncand) ? sidx : 0];
    const float* fj = (const float*)(out_u + (size_t)sj * ROWU + FN32_OFF) + sub * 32;
    float accv = 0.0f;
    int myIdx = g + t;
    for (int kk = 0; kk < D; kk += 128) {
      __syncthreads();
      int sbase = (c4 + sub * 16) & 63;
      #pragma unroll
      for (int q = 0; q < 8; q++) {
        float4 v = *(const float4*)(fj + kk + q * 4);   // already np-exact b
        int kl = sub * 32 + q * 4;
        Tm[(kl + 0) * 64 + sbase] = v.x;
        Tm[(kl + 1) * 64 + sbase] = v.y;
        Tm[(kl + 2) * 64 + sbase] = v.z;
        Tm[(kl + 3) * 64 + sbase] = v.w;
      }
      __syncthreads();
      if (t < 64) {
        for (int kl = 0; kl < 128; kl++) {
          int s = (t + ((kl >> 5) << 4)) & 63;
          accv = __fmaf_rn(ai[kk + kl], Tm[kl * 64 + s], accv);  // frozen order
        }
      }
    }
    if (t < 64 && myIdx < ncand) {
      int j = candIdx[myIdx];
      float xj = pos[2 * j], yj = pos[2 * j + 1];
      float dot2 = __fmaf_rn(yi, yj, __fmul_rn(xi, xj));
      float Ssum = __fadd_rn(sq_i, sqf[j]);
      float d2 = fmaxf(__fadd_rn(Ssum, -__fmul_rn(2.0f, dot2)), 0.0f);
      float arg = (-d2) / 5000.0f;
      float sp = (float)exp((double)arg);
      float u = __fmul_rn(__fadd_rn(__fmul_rn(lamf, accv), __fmul_rn(omlf, sp)), Tf);
      float e = (float)exp(-(double)u);
      candV[myIdx] = 1.0f / __fadd_rn(1.0f, e);
    }
  }
  __syncthreads();

  // --- wave-parallel selection: value desc, index asc (lax.top_k ties) ---
  for (int s = 0; s < KSEL; s++) {
    if (t < 64) {
      float bu = -1.0f; int bj = N, bs = 0;
      for (int c = t; c < ncand; c += 64) {
        float v = candV[c]; int j = candIdx[c];
        if (v > bu || (v == bu && j < bj)) { bu = v; bj = j; bs = c; }
      }
      #pragma unroll
      for (int off = 32; off > 0; off >>= 1) {
        float ov = __shfl_down(bu, off, 64);
        int   oj = __shfl_down(bj, off, 64);
        int   os = __shfl_down(bs, off, 64);
        if (ov > bu || (ov == bu && oj < bj)) { bu = ov; bj = oj; bs = os; }
      }
      if (t == 0) { selIdx[s] = bj; selVal[s] = bu; candV[bs] = -1.0f; }
    }
    __syncthreads();
  }

  // --- store sel list row-locally (scatter kernel finalizes) ---
  if (t < KSEL) {
    unsigned int* wr_u = out_u + (size_t)row * ROWU;
    wr_u[SELI_OFF + t] = (unsigned int)selIdx[t];
    ((float*)wr_u)[SELV_OFF + t] = selVal[t];
  }
}

// ---------------------------------------------------------------------------
// K4: finalize — zero row, scatter the 20 selected values.
// ---------------------------------------------------------------------------
__global__ __launch_bounds__(256) void scatter_kernel(float* __restrict__ out) {
  int row = blockIdx.x, t = threadIdx.x;
  float* orow = out + (size_t)row * N;
  int idx = 0; float val = 0.f;
  if (t < KSEL) {
    idx = (int)((const unsigned int*)orow)[SELI_OFF + t];
    val = orow[SELV_OFF + t];
  }
  __syncthreads();
  float4 z = {0.f, 0.f, 0.f, 0.f};
  for (int j = 4 * t; j < N; j += 1024) *(float4*)&orow[j] = z;
  __syncthreads();
  if (t < KSEL) orow[idx] = val;
}

extern "C" void kernel_launch(void* const* d_in, const int* in_sizes, int n_in,
                              void* d_out, int out_size, void* d_ws, size_t ws_size,
                              hipStream_t stream) {
  const float* feat = (const float*)d_in[0];
  const float* pos  = (const float*)d_in[1];
  const float* lamw = (const float*)d_in[2];
  const float* temp = (const float*)d_in[3];
  float* out = (float*)d_out;
  unsigned int* out_u = (unsigned int*)d_out;
  float* normf = (float*)d_ws;         // N floats
  float* sqf   = normf + N;            // N floats

  prep_kernel<<<N / 256, 256, 0, stream>>>(feat, pos, lamw, normf, sqf, out);
  fnorm_kernel<<<(N * D) / 1024, 256, 0, stream>>>(feat, normf, out_u);
  adj_kernel<<<2080, 256, 0, stream>>>(pos, sqf, lamw, temp, out_u);
  topk_kernel<<<N, 256, 0, stream>>>(pos, sqf, lamw, temp, out_u);
  scatter_kernel<<<N, 256, 0, stream>>>(out);
}

// Round 7
// 709.673 us; speedup vs baseline: 3.3369x; 1.0475x over previous
//
#include <hip/hip_runtime.h>
#include <hip/hip_fp16.h>
#include <math.h>

#define N 8192
#define D 512
#define KSEL 20
#define CAND_CAP 512
#define WINDOW 2.5e-3f
#define ROWU 8192
// fallback (R6) layout offsets inside out rows:
#define FN32_OFF 4096
#define FBF_OFF_US 9216
#define SELI_OFF 4864
#define SELV_OFF 4884

typedef __attribute__((ext_vector_type(8))) short short8;
typedef __attribute__((ext_vector_type(4))) float f32x4;

__device__ __forceinline__ unsigned short f2bf(float x) {
  unsigned int u = __float_as_uint(x);
  unsigned int r = u + 0x7FFFu + ((u >> 16) & 1u);
  return (unsigned short)(r >> 16);
}

__device__ __forceinline__ unsigned int packh2(float a, float b) {
  return (unsigned int)__half_as_ushort(__float2half(a)) |
         ((unsigned int)__half_as_ushort(__float2half(b)) << 16);
}

__device__ __forceinline__ void gld16(const unsigned short* g, unsigned short* l) {
  __builtin_amdgcn_global_load_lds(
      (const __attribute__((address_space(1))) unsigned int*)g,
      (__attribute__((address_space(3))) unsigned int*)l, 16, 0, 0);
}

// ---------------------------------------------------------------------------
// K1: np-exact fp32 prep (FROZEN — verified bit-exact R2..R6).
// ---------------------------------------------------------------------------
__global__ __launch_bounds__(256) void prep_kernel(
    const float* __restrict__ feat, const float* __restrict__ pos,
    const float* __restrict__ lamw,
    float* __restrict__ normf, float* __restrict__ sqf,
    float* __restrict__ out) {
  int row = blockIdx.x * 256 + threadIdx.x;
  if (row >= N) return;
  const float* f = feat + (size_t)row * D;
  float part[4];
  #pragma unroll
  for (int b = 0; b < 4; b++) {
    const float* a = f + b * 128;
    float r[8];
    #pragma unroll
    for (int j = 0; j < 8; j++) r[j] = __fmul_rn(a[j], a[j]);
    for (int i = 8; i < 128; i += 8) {
      #pragma unroll
      for (int j = 0; j < 8; j++)
        r[j] = __fadd_rn(r[j], __fmul_rn(a[i + j], a[i + j]));
    }
    part[b] = __fadd_rn(__fadd_rn(__fadd_rn(r[0], r[1]), __fadd_rn(r[2], r[3])),
                        __fadd_rn(__fadd_rn(r[4], r[5]), __fadd_rn(r[6], r[7])));
  }
  float s = __fadd_rn(__fadd_rn(part[0], part[1]), __fadd_rn(part[2], part[3]));
  float nrm = fmaxf(__fsqrt_rn(s), 1e-12f);
  normf[row] = nrm;
  float x = pos[2 * row], y = pos[2 * row + 1];
  sqf[row] = __fadd_rn(__fmul_rn(x, x), __fmul_rn(y, y));
  if (row == 0) {
    float e = (float)exp(-(double)lamw[0]);
    out[(size_t)N * N] = 1.0f / __fadd_rn(1.0f, e);
  }
}

// ===========================================================================
// BRANCH A (ws >= 24.2 MB): fnorm32 + packed bf16 in ws; fused finalize.
// ===========================================================================

__global__ __launch_bounds__(256) void fnorm_a(
    const float* __restrict__ feat, const float* __restrict__ normf,
    float* __restrict__ fn32, unsigned short* __restrict__ fnbf) {
  int i0 = (blockIdx.x * 256 + threadIdx.x) * 4;
  float n = normf[i0 >> 9];
  float4 v = *(const float4*)(feat + i0);
  float4 q;
  q.x = v.x / n; q.y = v.y / n; q.z = v.z / n; q.w = v.w / n;  // correctly-rounded = np
  *(float4*)(fn32 + i0) = q;
  uint2 o;
  o.x = (unsigned int)f2bf(q.x) | ((unsigned int)f2bf(q.y) << 16);
  o.y = (unsigned int)f2bf(q.z) | ((unsigned int)f2bf(q.w) << 16);
  *(uint2*)(fnbf + i0) = o;
}

// Symmetric bf16-MFMA filter from PACKED source. Triangular grid (2080).
// Writes pre-sigmoid fp16 pairs into out rows' first halves + mirror.
__global__ __launch_bounds__(256) void adj_a(
    const unsigned short* __restrict__ G,
    const float* __restrict__ pos, const float* __restrict__ sqf,
    const float* __restrict__ lamw, const float* __restrict__ temp,
    unsigned int* out_u) {
  __shared__ __align__(16) unsigned char smem[32768];
  unsigned short* As = (unsigned short*)smem;
  unsigned short* Bs = As + 8192;
  unsigned int* tileT = (unsigned int*)smem;

  int L = blockIdx.x;
  int by = (int)((129.0 - sqrt(129.0 * 129.0 - 8.0 * (double)L)) * 0.5);
  while (64 * (by + 1) - ((by + 1) * by) / 2 <= L) by++;
  while (64 * by - (by * (by - 1)) / 2 > L) by--;
  int bx = by + (L - (64 * by - (by * (by - 1)) / 2));

  int tid = threadIdx.x;
  int wave = tid >> 6, lane = tid & 63;
  int wr = (wave >> 1) * 64, wc = (wave & 1) * 64;
  int m = lane & 15, quad = lane >> 4;

  f32x4 acc[4][4];
  #pragma unroll
  for (int i = 0; i < 4; i++)
    #pragma unroll
    for (int j = 0; j < 4; j++) acc[i][j] = (f32x4){0.f, 0.f, 0.f, 0.f};

  for (int kt = 0; kt < D / 64; kt++) {
    #pragma unroll
    for (int i = 0; i < 4; i++) {
      int f = i * 256 + tid;
      int r = f >> 3, c = f & 7;
      int cs = (c + r) & 7;
      size_t goff = (size_t)r * D + kt * 64 + cs * 8;
      gld16(G + (size_t)(by * 128) * D + goff, &As[f * 8]);
      gld16(G + (size_t)(bx * 128) * D + goff, &Bs[f * 8]);
    }
    __syncthreads();
    #pragma unroll
    for (int h = 0; h < 2; h++) {
      short8 fa[4], fb[4];
      #pragma unroll
      for (int ti = 0; ti < 4; ti++) {
        int row = wr + ti * 16 + m;
        int cc = ((h * 4 + quad) - row) & 7;
        fa[ti] = *(const short8*)&As[row * 64 + cc * 8];
      }
      #pragma unroll
      for (int tj = 0; tj < 4; tj++) {
        int row = wc + tj * 16 + m;
        int cc = ((h * 4 + quad) - row) & 7;
        fb[tj] = *(const short8*)&Bs[row * 64 + cc * 8];
      }
      #pragma unroll
      for (int ti = 0; ti < 4; ti++)
        #pragma unroll
        for (int tj = 0; tj < 4; tj++)
          acc[ti][tj] = __builtin_amdgcn_mfma_f32_16x16x32_bf16(
              fa[ti], fb[tj], acc[ti][tj], 0, 0, 0);
    }
    __syncthreads();
  }

  float lam = 1.f / (1.f + __expf(-lamw[0]));
  float T = temp[0];
  float oml = 1.f - lam;
  bool offdiag = (bx != by);
  #pragma unroll
  for (int ti = 0; ti < 4; ti++) {
    int gi0 = by * 128 + wr + ti * 16 + quad * 4;
    float xi[4], yi[4], sqi[4];
    #pragma unroll
    for (int r = 0; r < 4; r++) {
      int gi = gi0 + r;
      xi[r] = pos[2 * gi]; yi[r] = pos[2 * gi + 1]; sqi[r] = sqf[gi];
    }
    #pragma unroll
    for (int tj = 0; tj < 4; tj++) {
      int gj = bx * 128 + wc + tj * 16 + m;
      float xj = pos[2 * gj], yj = pos[2 * gj + 1], sj = sqf[gj];
      f32x4 c = acc[ti][tj];
      float sv[4];
      #pragma unroll
      for (int r = 0; r < 4; r++) {
        float d2 = fmaxf(sqi[r] + sj - 2.f * (xi[r] * xj + yi[r] * yj), 0.f);
        float sp = __expf(-d2 * (1.f / 5000.f));
        sv[r] = (lam * c[r] + oml * sp) * T;
      }
      #pragma unroll
      for (int r = 0; r < 4; r++) {
        float pv = __shfl_xor(sv[r], 1, 64);
        if (!(lane & 1))
          out_u[(size_t)(gi0 + r) * ROWU + (gj >> 1)] = packh2(sv[r], pv);
      }
      if (offdiag) {
        int colL = wc + tj * 16 + m;
        int p0 = (wr + ti * 16) / 2 + quad * 2;
        tileT[colL * 64 + (p0 ^ (colL & 31))]       = packh2(sv[0], sv[1]);
        tileT[colL * 64 + ((p0 + 1) ^ (colL & 31))] = packh2(sv[2], sv[3]);
      }
    }
  }
  if (offdiag) {
    __syncthreads();
    int p = tid & 63, c0 = tid >> 6;
    for (int it = 0; it < 32; it++) {
      int c = it * 4 + c0;
      unsigned int w = tileT[c * 64 + (p ^ (c & 31))];
      out_u[(size_t)(bx * 128 + c) * ROWU + (by * 64 + p)] = w;
    }
  }
}

// topk with fused finalize: uint4 filter loads, 1-barrier/iter binary search,
// staged np-exact recompute from ws fn32 (FROZEN), selection, zero+scatter.
__global__ __launch_bounds__(256, 4) void topk_a(
    const float* __restrict__ pos, const float* __restrict__ sqf,
    const float* __restrict__ lamw, const float* __restrict__ temp,
    const float* __restrict__ fn32, float* __restrict__ out) {
  __shared__ float Tm[N];            // 32 KB staging
  __shared__ float ai[D];
  __shared__ int   redi[2][4];
  __shared__ int   candIdx[CAND_CAP];
  __shared__ float candV[CAND_CAP];
  __shared__ int   selIdx[KSEL];
  __shared__ float selVal[KSEL];
  __shared__ int   cnt;

  int row = blockIdx.x, t = threadIdx.x;
  int lane = t & 63, wid = t >> 6;
  float* orow = out + (size_t)row * N;
  const uint4* ou4 = (const uint4*)orow;
  const float* fn_i = fn32 + (size_t)row * D;

  float rv[32];
  #pragma unroll
  for (int q = 0; q < 4; q++) {
    uint4 u = ou4[t + 256 * q];
    unsigned int w[4] = {u.x, u.y, u.z, u.w};
    #pragma unroll
    for (int d = 0; d < 4; d++) {
      __half2 h2 = *reinterpret_cast<__half2*>(&w[d]);
      rv[8 * q + 2 * d]     = __low2float(h2);
      rv[8 * q + 2 * d + 1] = __high2float(h2);
    }
  }
  for (int k = t; k < D; k += 256) ai[k] = fn_i[k];   // np-exact a_i
  if (t == 0) cnt = 0;
  __syncthreads();

  // --- binary search: count_ge(lo) >= 20, one barrier per iter ---
  float lo = -8.f, hi = 8.f;
  for (int it = 0; it < 18; it++) {
    float mid = 0.5f * (lo + hi);
    int c = 0;
    #pragma unroll
    for (int q = 0; q < 32; q++) c += (rv[q] >= mid) ? 1 : 0;
    #pragma unroll
    for (int off = 32; off > 0; off >>= 1) c += __shfl_down(c, off, 64);
    if (lane == 0) redi[it & 1][wid] = c;
    __syncthreads();
    int tot = redi[it & 1][0] + redi[it & 1][1] + redi[it & 1][2] + redi[it & 1][3];
    if (tot >= KSEL) lo = mid; else hi = mid;
  }

  float thr = lo - WINDOW;
  #pragma unroll
  for (int q = 0; q < 32; q++) {
    if (rv[q] >= thr) {
      int p = atomicAdd(&cnt, 1);
      if (p < CAND_CAP) candIdx[p] = 8 * (t + 256 * (q >> 3)) + (q & 7);
    }
  }
  __syncthreads();
  int ncand = min(cnt, CAND_CAP);

  // --- staged np-exact recompute (FROZEN value arithmetic) ---
  float lamf;
  { float e = (float)exp(-(double)lamw[0]); lamf = 1.0f / __fadd_rn(1.0f, e); }
  float omlf = __fadd_rn(1.0f, -lamf);
  float Tf = temp[0];
  float sq_i = sqf[row];
  float xi = pos[2 * row], yi = pos[2 * row + 1];
  int c4 = t >> 2, sub = t & 3;

  for (int g = 0; g < ncand; g += 64) {
    int sidx = g + c4;
    int sj = candIdx[(sidx < ncand) ? sidx : 0];
    const float* fj = fn32 + (size_t)sj * D + sub * 32;
    float accv = 0.0f;
    int myIdx = g + t;
    for (int kk = 0; kk < D; kk += 128) {
      __syncthreads();
      int sbase = (c4 + sub * 16) & 63;
      #pragma unroll
      for (int q = 0; q < 8; q++) {
        float4 v = *(const float4*)(fj + kk + q * 4);
        int kl = sub * 32 + q * 4;
        Tm[(kl + 0) * 64 + sbase] = v.x;
        Tm[(kl + 1) * 64 + sbase] = v.y;
        Tm[(kl + 2) * 64 + sbase] = v.z;
        Tm[(kl + 3) * 64 + sbase] = v.w;
      }
      __syncthreads();
      if (t < 64) {
        for (int kl = 0; kl < 128; kl++) {
          int s = (t + ((kl >> 5) << 4)) & 63;
          accv = __fmaf_rn(ai[kk + kl], Tm[kl * 64 + s], accv);  // frozen order
        }
      }
    }
    if (t < 64 && myIdx < ncand) {
      int j = candIdx[myIdx];
      float xj = pos[2 * j], yj = pos[2 * j + 1];
      float dot2 = __fmaf_rn(yi, yj, __fmul_rn(xi, xj));
      float Ssum = __fadd_rn(sq_i, sqf[j]);
      float d2 = fmaxf(__fadd_rn(Ssum, -__fmul_rn(2.0f, dot2)), 0.0f);
      float arg = (-d2) / 5000.0f;
      float sp = (float)exp((double)arg);
      float u = __fmul_rn(__fadd_rn(__fmul_rn(lamf, accv), __fmul_rn(omlf, sp)), Tf);
      float e = (float)exp(-(double)u);
      candV[myIdx] = 1.0f / __fadd_rn(1.0f, e);
    }
  }
  __syncthreads();

  // --- selection: value desc, index asc (lax.top_k ties) ---
  for (int s = 0; s < KSEL; s++) {
    if (t < 64) {
      float bu = -1.0f; int bj = N, bs = 0;
      for (int c = t; c < ncand; c += 64) {
        float v = candV[c]; int j = candIdx[c];
        if (v > bu || (v == bu && j < bj)) { bu = v; bj = j; bs = c; }
      }
      #pragma unroll
      for (int off = 32; off > 0; off >>= 1) {
        float ov = __shfl_down(bu, off, 64);
        int   oj = __shfl_down(bj, off, 64);
        int   os = __shfl_down(bs, off, 64);
        if (ov > bu || (ov == bu && oj < bj)) { bu = ov; bj = oj; bs = os; }
      }
      if (t == 0) { selIdx[s] = bj; selVal[s] = bu; candV[bs] = -1.0f; }
    }
    __syncthreads();
  }

  // --- fused finalize: zero own row, scatter 20 values ---
  float4 z4 = {0.f, 0.f, 0.f, 0.f};
  for (int j = 4 * t; j < N; j += 1024) *(float4*)&orow[j] = z4;
  __syncthreads();
  if (t < KSEL) orow[selIdx[t]] = selVal[t];
}

// ===========================================================================
// BRANCH B (fallback, R6-proven pipeline verbatim)
// ===========================================================================

__global__ __launch_bounds__(256) void fnorm_fb(
    const float* __restrict__ feat, const float* __restrict__ normf,
    unsigned int* __restrict__ out_u) {
  int i0 = (blockIdx.x * 256 + threadIdx.x) * 4;
  int row = i0 >> 9, k = i0 & (D - 1);
  float n = normf[row];
  float4 v = *(const float4*)(feat + i0);
  float4 q;
  q.x = v.x / n; q.y = v.y / n; q.z = v.z / n; q.w = v.w / n;
  float* f32dst = (float*)(out_u + (size_t)row * ROWU + FN32_OFF);
  *(float4*)(f32dst + k) = q;
  unsigned int lo = (unsigned int)f2bf(q.x) | ((unsigned int)f2bf(q.y) << 16);
  unsigned int hi = (unsigned int)f2bf(q.z) | ((unsigned int)f2bf(q.w) << 16);
  uint2 o; o.x = lo; o.y = hi;
  *(uint2*)(out_u + (size_t)row * ROWU + (FBF_OFF_US >> 1) + (k >> 1)) = o;
}

__global__ __launch_bounds__(256) void adj_fb(
    const float* __restrict__ pos, const float* __restrict__ sqf,
    const float* __restrict__ lamw, const float* __restrict__ temp,
    unsigned int* out_u) {
  __shared__ __align__(16) unsigned char smem[32768];
  unsigned short* As = (unsigned short*)smem;
  unsigned short* Bs = As + 8192;
  unsigned int* tileT = (unsigned int*)smem;
  const unsigned short* G = (const unsigned short*)out_u;

  int L = blockIdx.x;
  int by = (int)((129.0 - sqrt(129.0 * 129.0 - 8.0 * (double)L)) * 0.5);
  while (64 * (by + 1) - ((by + 1) * by) / 2 <= L) by++;
  while (64 * by - (by * (by - 1)) / 2 > L) by--;
  int bx = by + (L - (64 * by - (by * (by - 1)) / 2));

  int tid = threadIdx.x;
  int wave = tid >> 6, lane = tid & 63;
  int wr = (wave >> 1) * 64, wc = (wave & 1) * 64;
  int m = lane & 15, quad = lane >> 4;

  f32x4 acc[4][4];
  #pragma unroll
  for (int i = 0; i < 4; i++)
    #pragma unroll
    for (int j = 0; j < 4; j++) acc[i][j] = (f32x4){0.f, 0.f, 0.f, 0.f};

  for (int kt = 0; kt < D / 64; kt++) {
    #pragma unroll
    for (int i = 0; i < 4; i++) {
      int f = i * 256 + tid;
      int r = f >> 3, c = f & 7;
      int cs = (c + r) & 7;
      size_t koff = (size_t)FBF_OFF_US + kt * 64 + cs * 8;
      gld16(G + (size_t)(by * 128 + r) * (2 * ROWU) + koff, &As[f * 8]);
      gld16(G + (size_t)(bx * 128 + r) * (2 * ROWU) + koff, &Bs[f * 8]);
    }
    __syncthreads();
    #pragma unroll
    for (int h = 0; h < 2; h++) {
      short8 fa[4], fb[4];
      #pragma unroll
      for (int ti = 0; ti < 4; ti++) {
        int row = wr + ti * 16 + m;
        int cc = ((h * 4 + quad) - row) & 7;
        fa[ti] = *(const short8*)&As[row * 64 + cc * 8];
      }
      #pragma unroll
      for (int tj = 0; tj < 4; tj++) {
        int row = wc + tj * 16 + m;
        int cc = ((h * 4 + quad) - row) & 7;
        fb[tj] = *(const short8*)&Bs[row * 64 + cc * 8];
      }
      #pragma unroll
      for (int ti = 0; ti < 4; ti++)
        #pragma unroll
        for (int tj = 0; tj < 4; tj++)
          acc[ti][tj] = __builtin_amdgcn_mfma_f32_16x16x32_bf16(
              fa[ti], fb[tj], acc[ti][tj], 0, 0, 0);
    }
    __syncthreads();
  }

  float lam = 1.f / (1.f + __expf(-lamw[0]));
  float T = temp[0];
  float oml = 1.f - lam;
  bool offdiag = (bx != by);
  #pragma unroll
  for (int ti = 0; ti < 4; ti++) {
    int gi0 = by * 128 + wr + ti * 16 + quad * 4;
    float xi[4], yi[4], sqi[4];
    #pragma unroll
    for (int r = 0; r < 4; r++) {
      int gi = gi0 + r;
      xi[r] = pos[2 * gi]; yi[r] = pos[2 * gi + 1]; sqi[r] = sqf[gi];
    }
    #pragma unroll
    for (int tj = 0; tj < 4; tj++) {
      int gj = bx * 128 + wc + tj * 16 + m;
      float xj = pos[2 * gj], yj = pos[2 * gj + 1], sj = sqf[gj];
      f32x4 c = acc[ti][tj];
      float sv[4];
      #pragma unroll
      for (int r = 0; r < 4; r++) {
        float d2 = fmaxf(sqi[r] + sj - 2.f * (xi[r] * xj + yi[r] * yj), 0.f);
        float sp = __expf(-d2 * (1.f / 5000.f));
        sv[r] = (lam * c[r] + oml * sp) * T;
      }
      #pragma unroll
      for (int r = 0; r < 4; r++) {
        float pv = __shfl_xor(sv[r], 1, 64);
        if (!(lane & 1))
          out_u[(size_t)(gi0 + r) * ROWU + (gj >> 1)] = packh2(sv[r], pv);
      }
      if (offdiag) {
        int colL = wc + tj * 16 + m;
        int p0 = (wr + ti * 16) / 2 + quad * 2;
        tileT[colL * 64 + (p0 ^ (colL & 31))]       = packh2(sv[0], sv[1]);
        tileT[colL * 64 + ((p0 + 1) ^ (colL & 31))] = packh2(sv[2], sv[3]);
      }
    }
  }
  if (offdiag) {
    __syncthreads();
    int p = tid & 63, c0 = tid >> 6;
    for (int it = 0; it < 32; it++) {
      int c = it * 4 + c0;
      unsigned int w = tileT[c * 64 + (p ^ (c & 31))];
      out_u[(size_t)(bx * 128 + c) * ROWU + (by * 64 + p)] = w;
    }
  }
}

__global__ __launch_bounds__(256, 4) void topk_fb(
    const float* __restrict__ pos, const float* __restrict__ sqf,
    const float* __restrict__ lamw, const float* __restrict__ temp,
    unsigned int* out_u) {
  __shared__ float Tm[N];
  __shared__ float ai[D];
  __shared__ int   redi[4];
  __shared__ int   candIdx[CAND_CAP];
  __shared__ float candV[CAND_CAP];
  __shared__ int   selIdx[KSEL];
  __shared__ float selVal[KSEL];
  __shared__ int   cnt;

  int row = blockIdx.x, t = threadIdx.x;
  int lane = t & 63, wid = t >> 6;
  const unsigned int* ou = out_u + (size_t)row * ROWU;
  const float* fn32_i = (const float*)(ou + FN32_OFF);

  float rv[32];
  #pragma unroll
  for (int q = 0; q < 16; q++) {
    unsigned int u = ou[t + 256 * q];
    __half2 h2 = *reinterpret_cast<__half2*>(&u);
    rv[2 * q]     = __low2float(h2);
    rv[2 * q + 1] = __high2float(h2);
  }
  for (int k = t; k < D; k += 256) ai[k] = fn32_i[k];
  if (t == 0) cnt = 0;
  __syncthreads();

  float lo = -8.f, hi = 8.f;
  for (int it = 0; it < 18; it++) {
    float mid = 0.5f * (lo + hi);
    int c = 0;
    #pragma unroll
    for (int q = 0; q < 32; q++) c += (rv[q] >= mid) ? 1 : 0;
    #pragma unroll
    for (int off = 32; off > 0; off >>= 1) c += __shfl_down(c, off, 64);
    __syncthreads();
    if (lane == 0) redi[wid] = c;
    __syncthreads();
    int tot = redi[0] + redi[1] + redi[2] + redi[3];
    if (tot >= KSEL) lo = mid; else hi = mid;
  }

  float thr = lo - WINDOW;
  #pragma unroll
  for (int q = 0; q < 32; q++) {
    if (rv[q] >= thr) {
      int p = atomicAdd(&cnt, 1);
      if (p < CAND_CAP) candIdx[p] = 2 * (t + 256 * (q >> 1)) + (q & 1);
    }
  }
  __syncthreads();
  int ncand = min(cnt, CAND_CAP);

  float lamf;
  { float e = (float)exp(-(double)lamw[0]); lamf = 1.0f / __fadd_rn(1.0f, e); }
  float omlf = __fadd_rn(1.0f, -lamf);
  float Tf = temp[0];
  float sq_i = sqf[row];
  float xi = pos[2 * row], yi = pos[2 * row + 1];
  int c4 = t >> 2, sub = t & 3;

  for (int g = 0; g < ncand; g += 64) {
    int sidx = g + c4;
    int sj = candIdx[(sidx < ncand) ? sidx : 0];
    const float* fj = (const float*)(out_u + (size_t)sj * ROWU + FN32_OFF) + sub * 32;
    float accv = 0.0f;
    int myIdx = g + t;
    for (int kk = 0; kk < D; kk += 128) {
      __syncthreads();
      int sbase = (c4 + sub * 16) & 63;
      #pragma unroll
      for (int q = 0; q < 8; q++) {
        float4 v = *(const float4*)(fj + kk + q * 4);
        int kl = sub * 32 + q * 4;
        Tm[(kl + 0) * 64 + sbase] = v.x;
        Tm[(kl + 1) * 64 + sbase] = v.y;
        Tm[(kl + 2) * 64 + sbase] = v.z;
        Tm[(kl + 3) * 64 + sbase] = v.w;
      }
      __syncthreads();
      if (t < 64) {
        for (int kl = 0; kl < 128; kl++) {
          int s = (t + ((kl >> 5) << 4)) & 63;
          accv = __fmaf_rn(ai[kk + kl], Tm[kl * 64 + s], accv);
        }
      }
    }
    if (t < 64 && myIdx < ncand) {
      int j = candIdx[myIdx];
      float xj = pos[2 * j], yj = pos[2 * j + 1];
      float dot2 = __fmaf_rn(yi, yj, __fmul_rn(xi, xj));
      float Ssum = __fadd_rn(sq_i, sqf[j]);
      float d2 = fmaxf(__fadd_rn(Ssum, -__fmul_rn(2.0f, dot2)), 0.0f);
      float arg = (-d2) / 5000.0f;
      float sp = (float)exp((double)arg);
      float u = __fmul_rn(__fadd_rn(__fmul_rn(lamf, accv), __fmul_rn(omlf, sp)), Tf);
      float e = (float)exp(-(double)u);
      candV[myIdx] = 1.0f / __fadd_rn(1.0f, e);
    }
  }
  __syncthreads();

  for (int s = 0; s < KSEL; s++) {
    if (t < 64) {
      float bu = -1.0f; int bj = N, bs = 0;
      for (int c = t; c < ncand; c += 64) {
        float v = candV[c]; int j = candIdx[c];
        if (v > bu || (v == bu && j < bj)) { bu = v; bj = j; bs = c; }
      }
      #pragma unroll
      for (int off = 32; off > 0; off >>= 1) {
        float ov = __shfl_down(bu, off, 64);
        int   oj = __shfl_down(bj, off, 64);
        int   os = __shfl_down(bs, off, 64);
        if (ov > bu || (ov == bu && oj < bj)) { bu = ov; bj = oj; bs = os; }
      }
      if (t == 0) { selIdx[s] = bj; selVal[s] = bu; candV[bs] = -1.0f; }
    }
    __syncthreads();
  }

  if (t < KSEL) {
    unsigned int* wr_u = out_u + (size_t)row * ROWU;
    wr_u[SELI_OFF + t] = (unsigned int)selIdx[t];
    ((float*)wr_u)[SELV_OFF + t] = selVal[t];
  }
}

__global__ __launch_bounds__(256) void scatter_fb(float* __restrict__ out) {
  int row = blockIdx.x, t = threadIdx.x;
  float* orow = out + (size_t)row * N;
  int idx = 0; float val = 0.f;
  if (t < KSEL) {
    idx = (int)((const unsigned int*)orow)[SELI_OFF + t];
    val = orow[SELV_OFF + t];
  }
  __syncthreads();
  float4 z = {0.f, 0.f, 0.f, 0.f};
  for (int j = 4 * t; j < N; j += 1024) *(float4*)&orow[j] = z;
  __syncthreads();
  if (t < KSEL) orow[idx] = val;
}

extern "C" void kernel_launch(void* const* d_in, const int* in_sizes, int n_in,
                              void* d_out, int out_size, void* d_ws, size_t ws_size,
                              hipStream_t stream) {
  const float* feat = (const float*)d_in[0];
  const float* pos  = (const float*)d_in[1];
  const float* lamw = (const float*)d_in[2];
  const float* temp = (const float*)d_in[3];
  float* out = (float*)d_out;
  unsigned int* out_u = (unsigned int*)d_out;
  float* normf = (float*)d_ws;                         // N floats
  float* sqf   = normf + N;                            // N floats
  float* fn32  = sqf + N;                              // N*D floats (16 MB)
  unsigned short* fnbf = (unsigned short*)(fn32 + (size_t)N * D);  // N*D bf16 (8 MB)
  size_t need = (size_t)2 * N * 4 + (size_t)N * D * 4 + (size_t)N * D * 2;

  prep_kernel<<<N / 256, 256, 0, stream>>>(feat, pos, lamw, normf, sqf, out);
  if (ws_size >= need) {
    fnorm_a<<<(N * D) / 1024, 256, 0, stream>>>(feat, normf, fn32, fnbf);
    adj_a<<<2080, 256, 0, stream>>>(fnbf, pos, sqf, lamw, temp, out_u);
    topk_a<<<N, 256, 0, stream>>>(pos, sqf, lamw, temp, fn32, out);
  } else {
    fnorm_fb<<<(N * D) / 1024, 256, 0, stream>>>(feat, normf, out_u);
    adj_fb<<<2080, 256, 0, stream>>>(pos, sqf, lamw, temp, out_u);
    topk_fb<<<N, 256, 0, stream>>>(pos, sqf, lamw, temp, out_u);
    scatter_fb<<<N, 256, 0, stream>>>(out);
  }
}

// Round 8
// 588.140 us; speedup vs baseline: 4.0264x; 1.2066x over previous
//
#include <hip/hip_runtime.h>
#include <hip/hip_fp16.h>
#include <math.h>

#define N 8192
#define D 512
#define KSEL 20
#define CAND_CAP 384
#define WINDOW 2.5e-3f
#define BS_EXTRA 6.2e-4f   // binary-search resolution slack (2.5/4096)
#define ROWU 8192

typedef __attribute__((ext_vector_type(8))) short short8;
typedef __attribute__((ext_vector_type(4))) float f32x4;

__device__ __forceinline__ unsigned short f2bf(float x) {
  unsigned int u = __float_as_uint(x);
  unsigned int r = u + 0x7FFFu + ((u >> 16) & 1u);
  return (unsigned short)(r >> 16);
}

__device__ __forceinline__ unsigned int packh2(float a, float b) {
  return (unsigned int)__half_as_ushort(__float2half(a)) |
         ((unsigned int)__half_as_ushort(__float2half(b)) << 16);
}

__device__ __forceinline__ void gld16(const unsigned short* g, unsigned short* l) {
  __builtin_amdgcn_global_load_lds(
      (const __attribute__((address_space(1))) unsigned int*)g,
      (__attribute__((address_space(3))) unsigned int*)l, 16, 0, 0);
}

// ---------------------------------------------------------------------------
// K1: np-exact fp32 prep (FROZEN — verified bit-exact R2..R7).
// ---------------------------------------------------------------------------
__global__ __launch_bounds__(256) void prep_kernel(
    const float* __restrict__ feat, const float* __restrict__ pos,
    const float* __restrict__ lamw,
    float* __restrict__ normf, float* __restrict__ sqf,
    float* __restrict__ out) {
  int row = blockIdx.x * 256 + threadIdx.x;
  if (row >= N) return;
  const float* f = feat + (size_t)row * D;
  float part[4];
  #pragma unroll
  for (int b = 0; b < 4; b++) {
    const float* a = f + b * 128;
    float r[8];
    #pragma unroll
    for (int j = 0; j < 8; j++) r[j] = __fmul_rn(a[j], a[j]);
    for (int i = 8; i < 128; i += 8) {
      #pragma unroll
      for (int j = 0; j < 8; j++)
        r[j] = __fadd_rn(r[j], __fmul_rn(a[i + j], a[i + j]));
    }
    part[b] = __fadd_rn(__fadd_rn(__fadd_rn(r[0], r[1]), __fadd_rn(r[2], r[3])),
                        __fadd_rn(__fadd_rn(r[4], r[5]), __fadd_rn(r[6], r[7])));
  }
  float s = __fadd_rn(__fadd_rn(part[0], part[1]), __fadd_rn(part[2], part[3]));
  float nrm = fmaxf(__fsqrt_rn(s), 1e-12f);
  normf[row] = nrm;
  float x = pos[2 * row], y = pos[2 * row + 1];
  sqf[row] = __fadd_rn(__fmul_rn(x, x), __fmul_rn(y, y));
  if (row == 0) {
    float e = (float)exp(-(double)lamw[0]);
    out[(size_t)N * N] = 1.0f / __fadd_rn(1.0f, e);
  }
}

// ---------------------------------------------------------------------------
// K1b: np-exact fp32 normalized features (ws) + bf16 copy for MFMA filter.
// ---------------------------------------------------------------------------
__global__ __launch_bounds__(256) void fnorm_kernel(
    const float* __restrict__ feat, const float* __restrict__ normf,
    float* __restrict__ fn32, unsigned short* __restrict__ fnbf) {
  int i0 = (blockIdx.x * 256 + threadIdx.x) * 4;
  float n = normf[i0 >> 9];
  float4 v = *(const float4*)(feat + i0);
  float4 q;
  q.x = v.x / n; q.y = v.y / n; q.z = v.z / n; q.w = v.w / n;  // correctly-rounded = np
  *(float4*)(fn32 + i0) = q;
  uint2 o;
  o.x = (unsigned int)f2bf(q.x) | ((unsigned int)f2bf(q.y) << 16);
  o.y = (unsigned int)f2bf(q.z) | ((unsigned int)f2bf(q.w) << 16);
  *(uint2*)(fnbf + i0) = o;
}

// ---------------------------------------------------------------------------
// K2: symmetric bf16-MFMA filter (triangular grid, 2080 blocks) writing
// pre-sigmoid fp16 pairs into out rows' lower halves (+ mirrored tile).
// NEW: first 2048 blocks also fire-and-forget a 64 KB zero stripe covering
// the out rows' UPPER halves (drains under the GEMM; topk then only has to
// write the lower half).
// ---------------------------------------------------------------------------
__global__ __launch_bounds__(256) void adj_kernel(
    const unsigned short* __restrict__ G,
    const float* __restrict__ pos, const float* __restrict__ sqf,
    const float* __restrict__ lamw, const float* __restrict__ temp,
    unsigned int* out_u) {
  __shared__ __align__(16) unsigned char smem[32768];
  unsigned short* As = (unsigned short*)smem;
  unsigned short* Bs = As + 8192;
  unsigned int* tileT = (unsigned int*)smem;

  int L = blockIdx.x;
  int tid = threadIdx.x;

  // --- zero stripe of upper halves (rows' dwords [4096,8192)) ---
  if (L < 2048) {
    uint4 z = {0u, 0u, 0u, 0u};
    #pragma unroll
    for (int it = 0; it < 16; it++) {
      int g = L * 16384 + it * 1024 + tid * 4;
      int r = g >> 12, c = g & 4095;
      *(uint4*)(out_u + (size_t)r * ROWU + 4096 + c) = z;
    }
  }

  int by = (int)((129.0 - sqrt(129.0 * 129.0 - 8.0 * (double)L)) * 0.5);
  while (64 * (by + 1) - ((by + 1) * by) / 2 <= L) by++;
  while (64 * by - (by * (by - 1)) / 2 > L) by--;
  int bx = by + (L - (64 * by - (by * (by - 1)) / 2));

  int wave = tid >> 6, lane = tid & 63;
  int wr = (wave >> 1) * 64, wc = (wave & 1) * 64;
  int m = lane & 15, quad = lane >> 4;

  f32x4 acc[4][4];
  #pragma unroll
  for (int i = 0; i < 4; i++)
    #pragma unroll
    for (int j = 0; j < 4; j++) acc[i][j] = (f32x4){0.f, 0.f, 0.f, 0.f};

  for (int kt = 0; kt < D / 64; kt++) {
    #pragma unroll
    for (int i = 0; i < 4; i++) {
      int f = i * 256 + tid;
      int r = f >> 3, c = f & 7;
      int cs = (c + r) & 7;
      size_t goff = (size_t)r * D + kt * 64 + cs * 8;
      gld16(G + (size_t)(by * 128) * D + goff, &As[f * 8]);
      gld16(G + (size_t)(bx * 128) * D + goff, &Bs[f * 8]);
    }
    __syncthreads();
    #pragma unroll
    for (int h = 0; h < 2; h++) {
      short8 fa[4], fb[4];
      #pragma unroll
      for (int ti = 0; ti < 4; ti++) {
        int row = wr + ti * 16 + m;
        int cc = ((h * 4 + quad) - row) & 7;
        fa[ti] = *(const short8*)&As[row * 64 + cc * 8];
      }
      #pragma unroll
      for (int tj = 0; tj < 4; tj++) {
        int row = wc + tj * 16 + m;
        int cc = ((h * 4 + quad) - row) & 7;
        fb[tj] = *(const short8*)&Bs[row * 64 + cc * 8];
      }
      #pragma unroll
      for (int ti = 0; ti < 4; ti++)
        #pragma unroll
        for (int tj = 0; tj < 4; tj++)
          acc[ti][tj] = __builtin_amdgcn_mfma_f32_16x16x32_bf16(
              fa[ti], fb[tj], acc[ti][tj], 0, 0, 0);
    }
    __syncthreads();
  }

  float lam = 1.f / (1.f + __expf(-lamw[0]));
  float T = temp[0];
  float oml = 1.f - lam;
  bool offdiag = (bx != by);
  #pragma unroll
  for (int ti = 0; ti < 4; ti++) {
    int gi0 = by * 128 + wr + ti * 16 + quad * 4;
    float xi[4], yi[4], sqi[4];
    #pragma unroll
    for (int r = 0; r < 4; r++) {
      int gi = gi0 + r;
      xi[r] = pos[2 * gi]; yi[r] = pos[2 * gi + 1]; sqi[r] = sqf[gi];
    }
    #pragma unroll
    for (int tj = 0; tj < 4; tj++) {
      int gj = bx * 128 + wc + tj * 16 + m;
      float xj = pos[2 * gj], yj = pos[2 * gj + 1], sj = sqf[gj];
      f32x4 c = acc[ti][tj];
      float sv[4];
      #pragma unroll
      for (int r = 0; r < 4; r++) {
        float d2 = fmaxf(sqi[r] + sj - 2.f * (xi[r] * xj + yi[r] * yj), 0.f);
        float sp = __expf(-d2 * (1.f / 5000.f));
        sv[r] = (lam * c[r] + oml * sp) * T;
      }
      #pragma unroll
      for (int r = 0; r < 4; r++) {
        float pv = __shfl_xor(sv[r], 1, 64);
        if (!(lane & 1))
          out_u[(size_t)(gi0 + r) * ROWU + (gj >> 1)] = packh2(sv[r], pv);
      }
      if (offdiag) {
        int colL = wc + tj * 16 + m;
        int p0 = (wr + ti * 16) / 2 + quad * 2;
        tileT[colL * 64 + (p0 ^ (colL & 31))]       = packh2(sv[0], sv[1]);
        tileT[colL * 64 + ((p0 + 1) ^ (colL & 31))] = packh2(sv[2], sv[3]);
      }
    }
  }
  if (offdiag) {
    __syncthreads();
    int p = tid & 63, c0 = tid >> 6;
    for (int it = 0; it < 32; it++) {
      int c = it * 4 + c0;
      unsigned int w = tileT[c * 64 + (p ^ (c & 31))];
      out_u[(size_t)(bx * 128 + c) * ROWU + (by * 64 + p)] = w;
    }
  }
}

// ---------------------------------------------------------------------------
// K3: per-row exact top-20 (np-exact fp32 emulation FROZEN).
// Early lower-half zero; 12-iter binary search [-1,1.5]; candidates;
// 8x64-chunk staged recompute with prefetch (same k-order); wave0-only
// selection (no barriers); final scatter.
// ---------------------------------------------------------------------------
__global__ __launch_bounds__(256, 6) void topk_kernel(
    const float* __restrict__ pos, const float* __restrict__ sqf,
    const float* __restrict__ lamw, const float* __restrict__ temp,
    const float* __restrict__ fn32, float* __restrict__ out) {
  __shared__ float Tm[64 * 64];      // 16 KB staging (64 k x 64 cand)
  __shared__ float ai[D];
  __shared__ int   redi[2][4];
  __shared__ int   candIdx[CAND_CAP];
  __shared__ float candV[CAND_CAP];
  __shared__ int   selIdx[KSEL];
  __shared__ float selVal[KSEL];
  __shared__ int   cnt;

  int row = blockIdx.x, t = threadIdx.x;
  int lane = t & 63, wid = t >> 6;
  float* orow = out + (size_t)row * N;
  const uint4* ou4 = (const uint4*)orow;
  const float* fn_i = fn32 + (size_t)row * D;

  // filter -> regs; col of rv[8q+2d+e] = 8t + 2048q + 2d + e
  float rv[32];
  #pragma unroll
  for (int q = 0; q < 4; q++) {
    uint4 u = ou4[t + 256 * q];
    unsigned int w[4] = {u.x, u.y, u.z, u.w};
    #pragma unroll
    for (int d = 0; d < 4; d++) {
      __half2 h2 = *reinterpret_cast<__half2*>(&w[d]);
      rv[8 * q + 2 * d]     = __low2float(h2);
      rv[8 * q + 2 * d + 1] = __high2float(h2);
    }
  }
  for (int k = t; k < D; k += 256) ai[k] = fn_i[k];   // np-exact a_i
  if (t == 0) cnt = 0;
  __syncthreads();                    // all filter reads done

  // early zero of lower half (stores drain during the phases below)
  {
    float4 z4 = {0.f, 0.f, 0.f, 0.f};
    #pragma unroll
    for (int i = 0; i < 4; i++) *(float4*)&orow[4 * t + 1024 * i] = z4;
  }

  // --- binary search: count_ge(lo) >= 20, 12 iters on [-1, 1.5] ---
  float lo = -1.0f, hi = 1.5f;
  for (int it = 0; it < 12; it++) {
    float mid = 0.5f * (lo + hi);
    int c = 0;
    #pragma unroll
    for (int q = 0; q < 32; q++) c += (rv[q] >= mid) ? 1 : 0;
    #pragma unroll
    for (int off = 32; off > 0; off >>= 1) c += __shfl_down(c, off, 64);
    if (lane == 0) redi[it & 1][wid] = c;
    __syncthreads();
    int tot = redi[it & 1][0] + redi[it & 1][1] + redi[it & 1][2] + redi[it & 1][3];
    if (tot >= KSEL) lo = mid; else hi = mid;
  }

  float thr = lo - (WINDOW + BS_EXTRA);
  #pragma unroll
  for (int q = 0; q < 32; q++) {
    if (rv[q] >= thr) {
      int p = atomicAdd(&cnt, 1);
      if (p < CAND_CAP) candIdx[p] = 8 * (t + 256 * (q >> 3)) + (q & 7);
    }
  }
  __syncthreads();
  int ncand = min(cnt, CAND_CAP);

  // --- staged np-exact recompute (FROZEN arithmetic, same k order) ---
  float lamf;
  { float e = (float)exp(-(double)lamw[0]); lamf = 1.0f / __fadd_rn(1.0f, e); }
  float omlf = __fadd_rn(1.0f, -lamf);
  float Tf = temp[0];
  float sq_i = sqf[row];
  float xi = pos[2 * row], yi = pos[2 * row + 1];
  int c4 = t >> 2, sub = t & 3;
  int slot = (c4 + 16 * sub) & 63;    // 2-way bank aliasing = free

  for (int g = 0; g < ncand; g += 64) {
    int sidx = g + c4;
    int sj = candIdx[(sidx < ncand) ? sidx : 0];
    const float* fj = fn32 + (size_t)sj * D + sub * 16;  // this thread's 16 k per chunk
    float accv = 0.0f;
    int myIdx = g + t;
    float4 pv[4];
    #pragma unroll
    for (int q = 0; q < 4; q++) pv[q] = *(const float4*)(fj + 0 * 64 + q * 4);
    for (int ck = 0; ck < 8; ck++) {
      __syncthreads();                // previous chunk's chains done
      #pragma unroll
      for (int q = 0; q < 4; q++) {
        int kl = sub * 16 + q * 4;
        Tm[(kl + 0) * 64 + slot] = pv[q].x;
        Tm[(kl + 1) * 64 + slot] = pv[q].y;
        Tm[(kl + 2) * 64 + slot] = pv[q].z;
        Tm[(kl + 3) * 64 + slot] = pv[q].w;
      }
      __syncthreads();                // staging visible
      if (ck < 7) {
        #pragma unroll
        for (int q = 0; q < 4; q++) pv[q] = *(const float4*)(fj + (ck + 1) * 64 + q * 4);
      }
      if (t < 64) {
        int kk = ck * 64;
        for (int kl = 0; kl < 64; kl++) {
          int s = (t + 16 * (kl >> 4)) & 63;
          accv = __fmaf_rn(ai[kk + kl], Tm[kl * 64 + s], accv);  // frozen order
        }
      }
    }
    if (t < 64 && myIdx < ncand) {
      int j = candIdx[myIdx];
      float xj = pos[2 * j], yj = pos[2 * j + 1];
      float dot2 = __fmaf_rn(yi, yj, __fmul_rn(xi, xj));
      float Ssum = __fadd_rn(sq_i, sqf[j]);
      float d2 = fmaxf(__fadd_rn(Ssum, -__fmul_rn(2.0f, dot2)), 0.0f);
      float arg = (-d2) / 5000.0f;
      float sp = (float)exp((double)arg);
      float u = __fmul_rn(__fadd_rn(__fmul_rn(lamf, accv), __fmul_rn(omlf, sp)), Tf);
      float e = (float)exp(-(double)u);
      candV[myIdx] = 1.0f / __fadd_rn(1.0f, e);
    }
  }

  // --- selection: wave0 only (candV fully written by wave0), no barriers ---
  if (t < 64) {
    for (int s = 0; s < KSEL; s++) {
      float bu = -1.0f; int bj = N, bs = 0;
      for (int c = t; c < ncand; c += 64) {
        float v = candV[c]; int j = candIdx[c];
        if (v > bu || (v == bu && j < bj)) { bu = v; bj = j; bs = c; }
      }
      #pragma unroll
      for (int off = 32; off > 0; off >>= 1) {
        float ov = __shfl_down(bu, off, 64);
        int   oj = __shfl_down(bj, off, 64);
        int   os = __shfl_down(bs, off, 64);
        if (ov > bu || (ov == bu && oj < bj)) { bu = ov; bj = oj; bs = os; }
      }
      if (t == 0) { selIdx[s] = bj; selVal[s] = bu; candV[bs] = -1.0f; }
      // lane0's candV write must be visible to whole wave next round:
      __builtin_amdgcn_s_waitcnt(0);  // lgkmcnt(0)
    }
  }
  __syncthreads();                    // zero-stores + selIdx visible
  if (t < KSEL) orow[selIdx[t]] = selVal[t];
}

extern "C" void kernel_launch(void* const* d_in, const int* in_sizes, int n_in,
                              void* d_out, int out_size, void* d_ws, size_t ws_size,
                              hipStream_t stream) {
  const float* feat = (const float*)d_in[0];
  const float* pos  = (const float*)d_in[1];
  const float* lamw = (const float*)d_in[2];
  const float* temp = (const float*)d_in[3];
  float* out = (float*)d_out;
  unsigned int* out_u = (unsigned int*)d_out;
  float* normf = (float*)d_ws;                         // N floats
  float* sqf   = normf + N;                            // N floats
  float* fn32  = sqf + N;                              // N*D floats (16 MB)
  unsigned short* fnbf = (unsigned short*)(fn32 + (size_t)N * D);  // N*D bf16 (8 MB)

  prep_kernel<<<N / 256, 256, 0, stream>>>(feat, pos, lamw, normf, sqf, out);
  fnorm_kernel<<<(N * D) / 1024, 256, 0, stream>>>(feat, normf, fn32, fnbf);
  adj_kernel<<<2080, 256, 0, stream>>>(fnbf, pos, sqf, lamw, temp, out_u);
  topk_kernel<<<N, 256, 0, stream>>>(pos, sqf, lamw, temp, fn32, out);
}

// Round 9
// 581.986 us; speedup vs baseline: 4.0690x; 1.0106x over previous
//
#include <hip/hip_runtime.h>
#include <hip/hip_fp16.h>
#include <math.h>

#define N 8192
#define D 512
#define KSEL 20
#define CAND_CAP 384
#define WINDOW 2.5e-3f
#define BS_EXTRA 6.2e-4f
#define ROWU 8192
#define FS_A 4096   // filter row stride (dwords) in ws (packed)

typedef __attribute__((ext_vector_type(8))) short short8;
typedef __attribute__((ext_vector_type(4))) float f32x4;

__device__ __forceinline__ unsigned short f2bf(float x) {
  unsigned int u = __float_as_uint(x);
  unsigned int r = u + 0x7FFFu + ((u >> 16) & 1u);
  return (unsigned short)(r >> 16);
}

__device__ __forceinline__ unsigned int packh2(float a, float b) {
  return (unsigned int)__half_as_ushort(__float2half(a)) |
         ((unsigned int)__half_as_ushort(__float2half(b)) << 16);
}

__device__ __forceinline__ void gld16(const unsigned short* g, unsigned short* l) {
  __builtin_amdgcn_global_load_lds(
      (const __attribute__((address_space(1))) unsigned int*)g,
      (__attribute__((address_space(3))) unsigned int*)l, 16, 0, 0);
}

// swizzled LDS tile index: row in [0,128), colpair cp in [0,64). 16B-chunk XOR.
__device__ __forceinline__ int swz(int row, int cp) {
  return row * 64 + ((((cp >> 2) ^ (row & 15)) << 2) | (cp & 3));
}
__device__ __forceinline__ int swz4(int row, int q) {   // uint4 granularity
  return row * 64 + ((q ^ (row & 15)) << 2);
}

// ---------------------------------------------------------------------------
// K1: fused np-exact prep + fnorm. One wave per row (8 rows/wave).
// Norm uses the exact numpy pairwise tree: per-128-block 8 chains of 16
// sequential fadd(fmul), combined by shfl_xor 1/2/4 (identical tree), then
// parts combined xor8/xor16. Division per element correctly rounded (= np).
// ---------------------------------------------------------------------------
__global__ __launch_bounds__(256) void prep_kernel(
    const float* __restrict__ feat, const float* __restrict__ pos,
    const float* __restrict__ lamw,
    float* __restrict__ normf, float* __restrict__ sqf,
    float* __restrict__ fn32, unsigned short* __restrict__ fnbf,
    float* __restrict__ out) {
  __shared__ float rowbuf[4][512];
  int w = threadIdx.x >> 6, lane = threadIdx.x & 63;
  float* rb = rowbuf[w];
  for (int i = 0; i < 8; i++) {
    int row = blockIdx.x * 32 + w * 8 + i;
    const float* f = feat + (size_t)row * D;
    float4 v0 = *(const float4*)(f + 4 * lane);
    float4 v1 = *(const float4*)(f + 256 + 4 * lane);
    *(float4*)&rb[4 * lane] = v0;
    *(float4*)&rb[256 + 4 * lane] = v1;
    __builtin_amdgcn_s_waitcnt(0);           // lgkmcnt(0): LDS visible in-wave
    float s = 0.f;
    if (lane < 32) {
      int b = lane >> 3, j = lane & 7;
      const float* a = rb + b * 128 + j;
      float r = __fmul_rn(a[0], a[0]);
      #pragma unroll
      for (int k = 1; k < 16; k++)
        r = __fadd_rn(r, __fmul_rn(a[8 * k], a[8 * k]));
      r = __fadd_rn(r, __shfl_xor(r, 1, 64));     // (r0+r1) etc — commutative
      r = __fadd_rn(r, __shfl_xor(r, 2, 64));     // (r0+r1)+(r2+r3)
      r = __fadd_rn(r, __shfl_xor(r, 4, 64));     // part[b]
      r = __fadd_rn(r, __shfl_xor(r, 8, 64));     // p0+p1 / p2+p3
      r = __fadd_rn(r, __shfl_xor(r, 16, 64));    // total (numpy tree)
      s = r;
    }
    float st = __shfl(s, 0, 64);
    float nrm = fmaxf(__fsqrt_rn(st), 1e-12f);
    if (lane == 0) {
      normf[row] = nrm;
      float x = pos[2 * row], y = pos[2 * row + 1];
      sqf[row] = __fadd_rn(__fmul_rn(x, x), __fmul_rn(y, y));
      if (row == 0) {
        float e = (float)exp(-(double)lamw[0]);
        out[(size_t)N * N] = 1.0f / __fadd_rn(1.0f, e);
      }
    }
    float4 q0, q1;
    q0.x = v0.x / nrm; q0.y = v0.y / nrm; q0.z = v0.z / nrm; q0.w = v0.w / nrm;
    q1.x = v1.x / nrm; q1.y = v1.y / nrm; q1.z = v1.z / nrm; q1.w = v1.w / nrm;
    *(float4*)(fn32 + (size_t)row * D + 4 * lane) = q0;
    *(float4*)(fn32 + (size_t)row * D + 256 + 4 * lane) = q1;
    uint2 o0, o1;
    o0.x = (unsigned int)f2bf(q0.x) | ((unsigned int)f2bf(q0.y) << 16);
    o0.y = (unsigned int)f2bf(q0.z) | ((unsigned int)f2bf(q0.w) << 16);
    o1.x = (unsigned int)f2bf(q1.x) | ((unsigned int)f2bf(q1.y) << 16);
    o1.y = (unsigned int)f2bf(q1.z) | ((unsigned int)f2bf(q1.w) << 16);
    *(uint2*)(fnbf + (size_t)row * D + 4 * lane) = o0;
    *(uint2*)(fnbf + (size_t)row * D + 256 + 4 * lane) = o1;
  }
}

// ---------------------------------------------------------------------------
// K2: symmetric bf16-MFMA filter (triangular grid, 2080 blocks).
// Pre-sigmoid fp16 pairs -> filt (mode 0: packed ws; mode 1: out rows).
// Direct tile AND mirror both streamed via the 32-KB LDS tile, 1KB-coalesced.
// Zero stripes: mode 0 zeroes ALL of out[0,N*N); mode 1 only upper halves.
// ---------------------------------------------------------------------------
__global__ __launch_bounds__(256) void adj_kernel(
    const unsigned short* __restrict__ G,
    const float* __restrict__ pos, const float* __restrict__ sqf,
    const float* __restrict__ lamw, const float* __restrict__ temp,
    unsigned int* __restrict__ filt, int fs,
    unsigned int* __restrict__ out_u, int mode) {
  __shared__ __align__(16) unsigned char smem[32768];
  unsigned short* As = (unsigned short*)smem;
  unsigned short* Bs = As + 8192;
  unsigned int* tileT = (unsigned int*)smem;

  int L = blockIdx.x;
  int tid = threadIdx.x;

  if (L < 2048) {
    uint4 z = {0u, 0u, 0u, 0u};
    if (mode == 0) {
      // zero 128 KB linear stripe of out[0, N*N)
      size_t base = (size_t)L * 32768;
      #pragma unroll
      for (int it = 0; it < 32; it++)
        *(uint4*)(out_u + base + it * 1024 + tid * 4) = z;
    } else {
      #pragma unroll
      for (int it = 0; it < 16; it++) {
        int g = L * 16384 + it * 1024 + tid * 4;
        int r = g >> 12, c = g & 4095;
        *(uint4*)(out_u + (size_t)r * ROWU + 4096 + c) = z;
      }
    }
  }

  int by = (int)((129.0 - sqrt(129.0 * 129.0 - 8.0 * (double)L)) * 0.5);
  while (64 * (by + 1) - ((by + 1) * by) / 2 <= L) by++;
  while (64 * by - (by * (by - 1)) / 2 > L) by--;
  int bx = by + (L - (64 * by - (by * (by - 1)) / 2));

  int wave = tid >> 6, lane = tid & 63;
  int wr = (wave >> 1) * 64, wc = (wave & 1) * 64;
  int m = lane & 15, quad = lane >> 4;

  f32x4 acc[4][4];
  #pragma unroll
  for (int i = 0; i < 4; i++)
    #pragma unroll
    for (int j = 0; j < 4; j++) acc[i][j] = (f32x4){0.f, 0.f, 0.f, 0.f};

  for (int kt = 0; kt < D / 64; kt++) {
    #pragma unroll
    for (int i = 0; i < 4; i++) {
      int f = i * 256 + tid;
      int r = f >> 3, c = f & 7;
      int cs = (c + r) & 7;
      size_t goff = (size_t)r * D + kt * 64 + cs * 8;
      gld16(G + (size_t)(by * 128) * D + goff, &As[f * 8]);
      gld16(G + (size_t)(bx * 128) * D + goff, &Bs[f * 8]);
    }
    __syncthreads();
    #pragma unroll
    for (int h = 0; h < 2; h++) {
      short8 fa[4], fb[4];
      #pragma unroll
      for (int ti = 0; ti < 4; ti++) {
        int row = wr + ti * 16 + m;
        int cc = ((h * 4 + quad) - row) & 7;
        fa[ti] = *(const short8*)&As[row * 64 + cc * 8];
      }
      #pragma unroll
      for (int tj = 0; tj < 4; tj++) {
        int row = wc + tj * 16 + m;
        int cc = ((h * 4 + quad) - row) & 7;
        fb[tj] = *(const short8*)&Bs[row * 64 + cc * 8];
      }
      #pragma unroll
      for (int ti = 0; ti < 4; ti++)
        #pragma unroll
        for (int tj = 0; tj < 4; tj++)
          acc[ti][tj] = __builtin_amdgcn_mfma_f32_16x16x32_bf16(
              fa[ti], fb[tj], acc[ti][tj], 0, 0, 0);
    }
    __syncthreads();
  }

  float lam = 1.f / (1.f + __expf(-lamw[0]));
  float T = temp[0];
  float oml = 1.f - lam;
  bool offdiag = (bx != by);

  // epilogue: compute pre-sigmoid scores, pack column pairs into LDS tile
  #pragma unroll
  for (int ti = 0; ti < 4; ti++) {
    int gi0 = by * 128 + wr + ti * 16 + quad * 4;
    float xi[4], yi[4], sqi[4];
    #pragma unroll
    for (int r = 0; r < 4; r++) {
      int gi = gi0 + r;
      xi[r] = pos[2 * gi]; yi[r] = pos[2 * gi + 1]; sqi[r] = sqf[gi];
    }
    #pragma unroll
    for (int tj = 0; tj < 4; tj++) {
      int gj = bx * 128 + wc + tj * 16 + m;
      float xj = pos[2 * gj], yj = pos[2 * gj + 1], sj = sqf[gj];
      f32x4 c = acc[ti][tj];
      float sv[4];
      #pragma unroll
      for (int r = 0; r < 4; r++) {
        float d2 = fmaxf(sqi[r] + sj - 2.f * (xi[r] * xj + yi[r] * yj), 0.f);
        float sp = __expf(-d2 * (1.f / 5000.f));
        sv[r] = (lam * c[r] + oml * sp) * T;
      }
      int cpL = (wc + tj * 16 + m) >> 1;
      #pragma unroll
      for (int r = 0; r < 4; r++) {
        float pv = __shfl_xor(sv[r], 1, 64);
        if (!(lane & 1)) {
          int rowL = wr + ti * 16 + quad * 4 + r;
          tileT[swz(rowL, cpL)] = packh2(sv[r], pv);
        }
      }
    }
  }
  __syncthreads();

  // stream direct tile: 1KB-coalesced uint4 rows
  #pragma unroll
  for (int it = 0; it < 8; it++) {
    int idx4 = it * 256 + tid;
    int row = idx4 >> 4, q = idx4 & 15;
    uint4 v = *(uint4*)&tileT[swz4(row, q)];
    *(uint4*)(filt + (size_t)(by * 128 + row) * fs + bx * 64 + q * 4) = v;
  }

  // mirror: transpose-repack from the same LDS tile
  if (offdiag) {
    #pragma unroll
    for (int it = 0; it < 8; it++) {
      int idx4 = it * 256 + tid;
      int c = idx4 >> 4, q = idx4 & 15;
      unsigned int wv[4];
      #pragma unroll
      for (int d = 0; d < 4; d++) {
        int p = q * 4 + d;
        unsigned int lo = tileT[swz(2 * p, c >> 1)];
        unsigned int hi = tileT[swz(2 * p + 1, c >> 1)];
        unsigned int h0 = (c & 1) ? (lo >> 16) : (lo & 0xFFFFu);
        unsigned int h1 = (c & 1) ? (hi >> 16) : (hi & 0xFFFFu);
        wv[d] = h0 | (h1 << 16);
      }
      uint4 v; v.x = wv[0]; v.y = wv[1]; v.z = wv[2]; v.w = wv[3];
      *(uint4*)(filt + (size_t)(bx * 128 + c) * fs + by * 64 + q * 4) = v;
    }
  }
}

// ---------------------------------------------------------------------------
// K3: per-row exact top-20 (np-exact fp32 emulation FROZEN).
// mode 0: no bulk zero (adj zeroed out) — scatter only.
// ---------------------------------------------------------------------------
__global__ __launch_bounds__(256, 6) void topk_kernel(
    const float* __restrict__ pos, const float* __restrict__ sqf,
    const float* __restrict__ lamw, const float* __restrict__ temp,
    const float* __restrict__ fn32,
    const unsigned int* __restrict__ filt, int fs,
    float* __restrict__ out, int doZero) {
  __shared__ float Tm[64 * 64];
  __shared__ float ai[D];
  __shared__ int   redi[2][4];
  __shared__ int   candIdx[CAND_CAP];
  __shared__ float candV[CAND_CAP];
  __shared__ int   selIdx[KSEL];
  __shared__ float selVal[KSEL];
  __shared__ int   cnt;

  int row = blockIdx.x, t = threadIdx.x;
  int lane = t & 63, wid = t >> 6;
  float* orow = out + (size_t)row * N;
  const uint4* fu4 = (const uint4*)(filt + (size_t)row * fs);
  const float* fn_i = fn32 + (size_t)row * D;

  float rv[32];
  #pragma unroll
  for (int q = 0; q < 4; q++) {
    uint4 u = fu4[t + 256 * q];
    unsigned int w[4] = {u.x, u.y, u.z, u.w};
    #pragma unroll
    for (int d = 0; d < 4; d++) {
      __half2 h2 = *reinterpret_cast<__half2*>(&w[d]);
      rv[8 * q + 2 * d]     = __low2float(h2);
      rv[8 * q + 2 * d + 1] = __high2float(h2);
    }
  }
  for (int k = t; k < D; k += 256) ai[k] = fn_i[k];
  if (t == 0) cnt = 0;
  __syncthreads();

  if (doZero) {
    float4 z4 = {0.f, 0.f, 0.f, 0.f};
    #pragma unroll
    for (int i = 0; i < 4; i++) *(float4*)&orow[4 * t + 1024 * i] = z4;
  }

  float lo = -1.0f, hi = 1.5f;
  for (int it = 0; it < 12; it++) {
    float mid = 0.5f * (lo + hi);
    int c = 0;
    #pragma unroll
    for (int q = 0; q < 32; q++) c += (rv[q] >= mid) ? 1 : 0;
    #pragma unroll
    for (int off = 32; off > 0; off >>= 1) c += __shfl_down(c, off, 64);
    if (lane == 0) redi[it & 1][wid] = c;
    __syncthreads();
    int tot = redi[it & 1][0] + redi[it & 1][1] + redi[it & 1][2] + redi[it & 1][3];
    if (tot >= KSEL) lo = mid; else hi = mid;
  }

  float thr = lo - (WINDOW + BS_EXTRA);
  #pragma unroll
  for (int q = 0; q < 32; q++) {
    if (rv[q] >= thr) {
      int p = atomicAdd(&cnt, 1);
      if (p < CAND_CAP) candIdx[p] = 8 * (t + 256 * (q >> 3)) + (q & 7);
    }
  }
  __syncthreads();
  int ncand = min(cnt, CAND_CAP);

  float lamf;
  { float e = (float)exp(-(double)lamw[0]); lamf = 1.0f / __fadd_rn(1.0f, e); }
  float omlf = __fadd_rn(1.0f, -lamf);
  float Tf = temp[0];
  float sq_i = sqf[row];
  float xi = pos[2 * row], yi = pos[2 * row + 1];
  int c4 = t >> 2, sub = t & 3;
  int slot = (c4 + 16 * sub) & 63;

  for (int g = 0; g < ncand; g += 64) {
    int sidx = g + c4;
    int sj = candIdx[(sidx < ncand) ? sidx : 0];
    const float* fj = fn32 + (size_t)sj * D + sub * 16;
    float accv = 0.0f;
    int myIdx = g + t;
    float4 pv[4];
    #pragma unroll
    for (int q = 0; q < 4; q++) pv[q] = *(const float4*)(fj + q * 4);
    for (int ck = 0; ck < 8; ck++) {
      __syncthreads();
      #pragma unroll
      for (int q = 0; q < 4; q++) {
        int kl = sub * 16 + q * 4;
        Tm[(kl + 0) * 64 + slot] = pv[q].x;
        Tm[(kl + 1) * 64 + slot] = pv[q].y;
        Tm[(kl + 2) * 64 + slot] = pv[q].z;
        Tm[(kl + 3) * 64 + slot] = pv[q].w;
      }
      __syncthreads();
      if (ck < 7) {
        #pragma unroll
        for (int q = 0; q < 4; q++) pv[q] = *(const float4*)(fj + (ck + 1) * 64 + q * 4);
      }
      if (t < 64) {
        int kk = ck * 64;
        for (int kl = 0; kl < 64; kl++) {
          int s = (t + 16 * (kl >> 4)) & 63;
          accv = __fmaf_rn(ai[kk + kl], Tm[kl * 64 + s], accv);  // frozen order
        }
      }
    }
    if (t < 64 && myIdx < ncand) {
      int j = candIdx[myIdx];
      float xj = pos[2 * j], yj = pos[2 * j + 1];
      float dot2 = __fmaf_rn(yi, yj, __fmul_rn(xi, xj));
      float Ssum = __fadd_rn(sq_i, sqf[j]);
      float d2 = fmaxf(__fadd_rn(Ssum, -__fmul_rn(2.0f, dot2)), 0.0f);
      float arg = (-d2) / 5000.0f;
      float sp = (float)exp((double)arg);
      float u = __fmul_rn(__fadd_rn(__fmul_rn(lamf, accv), __fmul_rn(omlf, sp)), Tf);
      float e = (float)exp(-(double)u);
      candV[myIdx] = 1.0f / __fadd_rn(1.0f, e);
    }
  }

  if (t < 64) {
    for (int s = 0; s < KSEL; s++) {
      float bu = -1.0f; int bj = N, bs = 0;
      for (int c = t; c < ncand; c += 64) {
        float v = candV[c]; int j = candIdx[c];
        if (v > bu || (v == bu && j < bj)) { bu = v; bj = j; bs = c; }
      }
      #pragma unroll
      for (int off = 32; off > 0; off >>= 1) {
        float ov = __shfl_down(bu, off, 64);
        int   oj = __shfl_down(bj, off, 64);
        int   os = __shfl_down(bs, off, 64);
        if (ov > bu || (ov == bu && oj < bj)) { bu = ov; bj = oj; bs = os; }
      }
      if (t == 0) { selIdx[s] = bj; selVal[s] = bu; candV[bs] = -1.0f; }
      __builtin_amdgcn_s_waitcnt(0);
    }
  }
  __syncthreads();
  if (t < KSEL) orow[selIdx[t]] = selVal[t];
}

extern "C" void kernel_launch(void* const* d_in, const int* in_sizes, int n_in,
                              void* d_out, int out_size, void* d_ws, size_t ws_size,
                              hipStream_t stream) {
  const float* feat = (const float*)d_in[0];
  const float* pos  = (const float*)d_in[1];
  const float* lamw = (const float*)d_in[2];
  const float* temp = (const float*)d_in[3];
  float* out = (float*)d_out;
  unsigned int* out_u = (unsigned int*)d_out;

  float* normf = (float*)d_ws;                               // N f32
  float* sqf   = normf + N;                                  // N f32
  float* fn32  = sqf + N;                                    // N*D f32 (16 MB)
  unsigned short* fnbf = (unsigned short*)(fn32 + (size_t)N * D);  // 8 MB
  unsigned int* filtA = (unsigned int*)(fnbf + (size_t)N * D);     // 128 MB
  size_t needA = (size_t)2 * N * 4 + (size_t)N * D * 4 + (size_t)N * D * 2 +
                 (size_t)N * FS_A * 4;
  size_t needB = (size_t)2 * N * 4 + (size_t)N * D * 4 + (size_t)N * D * 2;

  prep_kernel<<<N / 32, 256, 0, stream>>>(feat, pos, lamw, normf, sqf,
                                          fn32, fnbf, out);
  if (ws_size >= needA) {
    adj_kernel<<<2080, 256, 0, stream>>>(fnbf, pos, sqf, lamw, temp,
                                         filtA, FS_A, out_u, 0);
    topk_kernel<<<N, 256, 0, stream>>>(pos, sqf, lamw, temp, fn32,
                                       filtA, FS_A, out, 0);
  } else {
    // fallback: filter lives in out rows' lower halves (R8-proven layout)
    (void)needB;
    adj_kernel<<<2080, 256, 0, stream>>>(fnbf, pos, sqf, lamw, temp,
                                         out_u, ROWU, out_u, 1);
    topk_kernel<<<N, 256, 0, stream>>>(pos, sqf, lamw, temp, fn32,
                                       out_u, ROWU, out, 1);
  }
}

// Round 10
// 570.766 us; speedup vs baseline: 4.1490x; 1.0197x over previous
//
#include <hip/hip_runtime.h>
#include <hip/hip_fp16.h>
#include <math.h>

#define N 8192
#define D 512
#define KSEL 20
#define CAND_CAP 256
#define WINDOW 2.5e-3f
#define BS_EXTRA 6.2e-4f
#define ROWU 8192
#define FS_A 4096

typedef __attribute__((ext_vector_type(8))) short short8;
typedef __attribute__((ext_vector_type(4))) float f32x4;

__device__ __forceinline__ unsigned short f2bf(float x) {
  unsigned int u = __float_as_uint(x);
  unsigned int r = u + 0x7FFFu + ((u >> 16) & 1u);
  return (unsigned short)(r >> 16);
}

__device__ __forceinline__ unsigned int packh2(float a, float b) {
  return (unsigned int)__half_as_ushort(__float2half(a)) |
         ((unsigned int)__half_as_ushort(__float2half(b)) << 16);
}

__device__ __forceinline__ void gld16(const unsigned short* g, unsigned short* l) {
  __builtin_amdgcn_global_load_lds(
      (const __attribute__((address_space(1))) unsigned int*)g,
      (__attribute__((address_space(3))) unsigned int*)l, 16, 0, 0);
}

__device__ __forceinline__ int swz(int row, int cp) {
  return row * 64 + ((((cp >> 2) ^ (row & 15)) << 2) | (cp & 3));
}
__device__ __forceinline__ int swz4(int row, int q) {
  return row * 64 + ((q ^ (row & 15)) << 2);
}

// ---------------------------------------------------------------------------
// K1: fused np-exact prep + fnorm (FROZEN — verified bit-exact R9).
// ---------------------------------------------------------------------------
__global__ __launch_bounds__(256) void prep_kernel(
    const float* __restrict__ feat, const float* __restrict__ pos,
    const float* __restrict__ lamw,
    float* __restrict__ normf, float* __restrict__ sqf,
    float* __restrict__ fn32, unsigned short* __restrict__ fnbf,
    float* __restrict__ out) {
  __shared__ float rowbuf[4][512];
  int w = threadIdx.x >> 6, lane = threadIdx.x & 63;
  float* rb = rowbuf[w];
  for (int i = 0; i < 8; i++) {
    int row = blockIdx.x * 32 + w * 8 + i;
    const float* f = feat + (size_t)row * D;
    float4 v0 = *(const float4*)(f + 4 * lane);
    float4 v1 = *(const float4*)(f + 256 + 4 * lane);
    *(float4*)&rb[4 * lane] = v0;
    *(float4*)&rb[256 + 4 * lane] = v1;
    __builtin_amdgcn_s_waitcnt(0);
    float s = 0.f;
    if (lane < 32) {
      int b = lane >> 3, j = lane & 7;
      const float* a = rb + b * 128 + j;
      float r = __fmul_rn(a[0], a[0]);
      #pragma unroll
      for (int k = 1; k < 16; k++)
        r = __fadd_rn(r, __fmul_rn(a[8 * k], a[8 * k]));
      r = __fadd_rn(r, __shfl_xor(r, 1, 64));
      r = __fadd_rn(r, __shfl_xor(r, 2, 64));
      r = __fadd_rn(r, __shfl_xor(r, 4, 64));
      r = __fadd_rn(r, __shfl_xor(r, 8, 64));
      r = __fadd_rn(r, __shfl_xor(r, 16, 64));
      s = r;
    }
    float st = __shfl(s, 0, 64);
    float nrm = fmaxf(__fsqrt_rn(st), 1e-12f);
    if (lane == 0) {
      normf[row] = nrm;
      float x = pos[2 * row], y = pos[2 * row + 1];
      sqf[row] = __fadd_rn(__fmul_rn(x, x), __fmul_rn(y, y));
      if (row == 0) {
        float e = (float)exp(-(double)lamw[0]);
        out[(size_t)N * N] = 1.0f / __fadd_rn(1.0f, e);
      }
    }
    float4 q0, q1;
    q0.x = v0.x / nrm; q0.y = v0.y / nrm; q0.z = v0.z / nrm; q0.w = v0.w / nrm;
    q1.x = v1.x / nrm; q1.y = v1.y / nrm; q1.z = v1.z / nrm; q1.w = v1.w / nrm;
    *(float4*)(fn32 + (size_t)row * D + 4 * lane) = q0;
    *(float4*)(fn32 + (size_t)row * D + 256 + 4 * lane) = q1;
    uint2 o0, o1;
    o0.x = (unsigned int)f2bf(q0.x) | ((unsigned int)f2bf(q0.y) << 16);
    o0.y = (unsigned int)f2bf(q0.z) | ((unsigned int)f2bf(q0.w) << 16);
    o1.x = (unsigned int)f2bf(q1.x) | ((unsigned int)f2bf(q1.y) << 16);
    o1.y = (unsigned int)f2bf(q1.z) | ((unsigned int)f2bf(q1.w) << 16);
    *(uint2*)(fnbf + (size_t)row * D + 4 * lane) = o0;
    *(uint2*)(fnbf + (size_t)row * D + 256 + 4 * lane) = o1;
  }
}

// ---------------------------------------------------------------------------
// K2: symmetric bf16-MFMA filter (unchanged from R9 — proven).
// ---------------------------------------------------------------------------
__global__ __launch_bounds__(256) void adj_kernel(
    const unsigned short* __restrict__ G,
    const float* __restrict__ pos, const float* __restrict__ sqf,
    const float* __restrict__ lamw, const float* __restrict__ temp,
    unsigned int* __restrict__ filt, int fs,
    unsigned int* __restrict__ out_u, int mode) {
  __shared__ __align__(16) unsigned char smem[32768];
  unsigned short* As = (unsigned short*)smem;
  unsigned short* Bs = As + 8192;
  unsigned int* tileT = (unsigned int*)smem;

  int L = blockIdx.x;
  int tid = threadIdx.x;

  if (L < 2048) {
    uint4 z = {0u, 0u, 0u, 0u};
    if (mode == 0) {
      size_t base = (size_t)L * 32768;
      #pragma unroll
      for (int it = 0; it < 32; it++)
        *(uint4*)(out_u + base + it * 1024 + tid * 4) = z;
    } else {
      #pragma unroll
      for (int it = 0; it < 16; it++) {
        int g = L * 16384 + it * 1024 + tid * 4;
        int r = g >> 12, c = g & 4095;
        *(uint4*)(out_u + (size_t)r * ROWU + 4096 + c) = z;
      }
    }
  }

  int by = (int)((129.0 - sqrt(129.0 * 129.0 - 8.0 * (double)L)) * 0.5);
  while (64 * (by + 1) - ((by + 1) * by) / 2 <= L) by++;
  while (64 * by - (by * (by - 1)) / 2 > L) by--;
  int bx = by + (L - (64 * by - (by * (by - 1)) / 2));

  int wave = tid >> 6, lane = tid & 63;
  int wr = (wave >> 1) * 64, wc = (wave & 1) * 64;
  int m = lane & 15, quad = lane >> 4;

  f32x4 acc[4][4];
  #pragma unroll
  for (int i = 0; i < 4; i++)
    #pragma unroll
    for (int j = 0; j < 4; j++) acc[i][j] = (f32x4){0.f, 0.f, 0.f, 0.f};

  for (int kt = 0; kt < D / 64; kt++) {
    #pragma unroll
    for (int i = 0; i < 4; i++) {
      int f = i * 256 + tid;
      int r = f >> 3, c = f & 7;
      int cs = (c + r) & 7;
      size_t goff = (size_t)r * D + kt * 64 + cs * 8;
      gld16(G + (size_t)(by * 128) * D + goff, &As[f * 8]);
      gld16(G + (size_t)(bx * 128) * D + goff, &Bs[f * 8]);
    }
    __syncthreads();
    #pragma unroll
    for (int h = 0; h < 2; h++) {
      short8 fa[4], fb[4];
      #pragma unroll
      for (int ti = 0; ti < 4; ti++) {
        int row = wr + ti * 16 + m;
        int cc = ((h * 4 + quad) - row) & 7;
        fa[ti] = *(const short8*)&As[row * 64 + cc * 8];
      }
      #pragma unroll
      for (int tj = 0; tj < 4; tj++) {
        int row = wc + tj * 16 + m;
        int cc = ((h * 4 + quad) - row) & 7;
        fb[tj] = *(const short8*)&Bs[row * 64 + cc * 8];
      }
      #pragma unroll
      for (int ti = 0; ti < 4; ti++)
        #pragma unroll
        for (int tj = 0; tj < 4; tj++)
          acc[ti][tj] = __builtin_amdgcn_mfma_f32_16x16x32_bf16(
              fa[ti], fb[tj], acc[ti][tj], 0, 0, 0);
    }
    __syncthreads();
  }

  float lam = 1.f / (1.f + __expf(-lamw[0]));
  float T = temp[0];
  float oml = 1.f - lam;
  bool offdiag = (bx != by);

  #pragma unroll
  for (int ti = 0; ti < 4; ti++) {
    int gi0 = by * 128 + wr + ti * 16 + quad * 4;
    float xi[4], yi[4], sqi[4];
    #pragma unroll
    for (int r = 0; r < 4; r++) {
      int gi = gi0 + r;
      xi[r] = pos[2 * gi]; yi[r] = pos[2 * gi + 1]; sqi[r] = sqf[gi];
    }
    #pragma unroll
    for (int tj = 0; tj < 4; tj++) {
      int gj = bx * 128 + wc + tj * 16 + m;
      float xj = pos[2 * gj], yj = pos[2 * gj + 1], sj = sqf[gj];
      f32x4 c = acc[ti][tj];
      float sv[4];
      #pragma unroll
      for (int r = 0; r < 4; r++) {
        float d2 = fmaxf(sqi[r] + sj - 2.f * (xi[r] * xj + yi[r] * yj), 0.f);
        float sp = __expf(-d2 * (1.f / 5000.f));
        sv[r] = (lam * c[r] + oml * sp) * T;
      }
      int cpL = (wc + tj * 16 + m) >> 1;
      #pragma unroll
      for (int r = 0; r < 4; r++) {
        float pv = __shfl_xor(sv[r], 1, 64);
        if (!(lane & 1)) {
          int rowL = wr + ti * 16 + quad * 4 + r;
          tileT[swz(rowL, cpL)] = packh2(sv[r], pv);
        }
      }
    }
  }
  __syncthreads();

  #pragma unroll
  for (int it = 0; it < 8; it++) {
    int idx4 = it * 256 + tid;
    int row = idx4 >> 4, q = idx4 & 15;
    uint4 v = *(uint4*)&tileT[swz4(row, q)];
    *(uint4*)(filt + (size_t)(by * 128 + row) * fs + bx * 64 + q * 4) = v;
  }

  if (offdiag) {
    #pragma unroll
    for (int it = 0; it < 8; it++) {
      int idx4 = it * 256 + tid;
      int c = idx4 >> 4, q = idx4 & 15;
      unsigned int wv[4];
      #pragma unroll
      for (int d = 0; d < 4; d++) {
        int p = q * 4 + d;
        unsigned int lo = tileT[swz(2 * p, c >> 1)];
        unsigned int hi = tileT[swz(2 * p + 1, c >> 1)];
        unsigned int h0 = (c & 1) ? (lo >> 16) : (lo & 0xFFFFu);
        unsigned int h1 = (c & 1) ? (hi >> 16) : (hi & 0xFFFFu);
        wv[d] = h0 | (h1 << 16);
      }
      uint4 v; v.x = wv[0]; v.y = wv[1]; v.z = wv[2]; v.w = wv[3];
      *(uint4*)(filt + (size_t)(bx * 128 + c) * fs + by * 64 + q * 4) = v;
    }
  }
}

// ---------------------------------------------------------------------------
// K3: per-row exact top-20 (np-exact fp32 value arithmetic FROZEN).
// NEW recompute: thread t owns candidate t — streams its contiguous fn32 row
// (double-buffered float4) and runs the frozen sequential-FMA chain with ai
// via LDS broadcast. No staging, no barriers, loads only for real candidates.
// ---------------------------------------------------------------------------
__global__ __launch_bounds__(256, 4) void topk_kernel(
    const float* __restrict__ pos, const float* __restrict__ sqf,
    const float* __restrict__ lamw, const float* __restrict__ temp,
    const float* __restrict__ fn32,
    const unsigned int* __restrict__ filt, int fs,
    float* __restrict__ out, int doZero) {
  __shared__ float ai[D];
  __shared__ int   redi[2][4];
  __shared__ int   candIdx[CAND_CAP];
  __shared__ float candV[CAND_CAP];
  __shared__ int   selIdx[KSEL];
  __shared__ float selVal[KSEL];
  __shared__ int   cnt;

  int row = blockIdx.x, t = threadIdx.x;
  int lane = t & 63, wid = t >> 6;
  float* orow = out + (size_t)row * N;
  const uint4* fu4 = (const uint4*)(filt + (size_t)row * fs);
  const float* fn_i = fn32 + (size_t)row * D;

  float rv[32];
  #pragma unroll
  for (int q = 0; q < 4; q++) {
    uint4 u = fu4[t + 256 * q];
    unsigned int w[4] = {u.x, u.y, u.z, u.w};
    #pragma unroll
    for (int d = 0; d < 4; d++) {
      __half2 h2 = *reinterpret_cast<__half2*>(&w[d]);
      rv[8 * q + 2 * d]     = __low2float(h2);
      rv[8 * q + 2 * d + 1] = __high2float(h2);
    }
  }
  for (int k = t; k < D; k += 256) ai[k] = fn_i[k];   // np-exact a_i
  if (t == 0) cnt = 0;
  __syncthreads();

  if (doZero) {
    float4 z4 = {0.f, 0.f, 0.f, 0.f};
    #pragma unroll
    for (int i = 0; i < 4; i++) *(float4*)&orow[4 * t + 1024 * i] = z4;
  }

  // --- binary search: count_ge(lo) >= 20, 12 iters on [-1, 1.5] ---
  float lo = -1.0f, hi = 1.5f;
  for (int it = 0; it < 12; it++) {
    float mid = 0.5f * (lo + hi);
    int c = 0;
    #pragma unroll
    for (int q = 0; q < 32; q++) c += (rv[q] >= mid) ? 1 : 0;
    #pragma unroll
    for (int off = 32; off > 0; off >>= 1) c += __shfl_down(c, off, 64);
    if (lane == 0) redi[it & 1][wid] = c;
    __syncthreads();
    int tot = redi[it & 1][0] + redi[it & 1][1] + redi[it & 1][2] + redi[it & 1][3];
    if (tot >= KSEL) lo = mid; else hi = mid;
  }

  float thr = lo - (WINDOW + BS_EXTRA);
  #pragma unroll
  for (int q = 0; q < 32; q++) {
    if (rv[q] >= thr) {
      int p = atomicAdd(&cnt, 1);
      if (p < CAND_CAP) candIdx[p] = 8 * (t + 256 * (q >> 3)) + (q & 7);
    }
  }
  __syncthreads();
  int ncand = min(cnt, CAND_CAP);

  // --- per-thread streamed np-exact recompute (FROZEN arithmetic) ---
  float lamf;
  { float e = (float)exp(-(double)lamw[0]); lamf = 1.0f / __fadd_rn(1.0f, e); }
  float omlf = __fadd_rn(1.0f, -lamf);
  float Tf = temp[0];
  float sq_i = sqf[row];
  float xi = pos[2 * row], yi = pos[2 * row + 1];

  if (t < ncand) {
    int j = candIdx[t];
    const float* fj = fn32 + (size_t)j * D;
    float accv = 0.0f;
    float4 buf[4], nxt[4];
    #pragma unroll
    for (int q = 0; q < 4; q++) buf[q] = *(const float4*)(fj + q * 4);
    for (int c16 = 0; c16 < 32; c16++) {
      if (c16 < 31) {
        #pragma unroll
        for (int q = 0; q < 4; q++)
          nxt[q] = *(const float4*)(fj + (c16 + 1) * 16 + q * 4);
      }
      #pragma unroll
      for (int q = 0; q < 4; q++) {
        float4 a4 = *(const float4*)&ai[c16 * 16 + q * 4];   // LDS broadcast
        accv = __fmaf_rn(a4.x, buf[q].x, accv);              // frozen k-order
        accv = __fmaf_rn(a4.y, buf[q].y, accv);
        accv = __fmaf_rn(a4.z, buf[q].z, accv);
        accv = __fmaf_rn(a4.w, buf[q].w, accv);
      }
      #pragma unroll
      for (int q = 0; q < 4; q++) buf[q] = nxt[q];
    }
    float xj = pos[2 * j], yj = pos[2 * j + 1];
    float dot2 = __fmaf_rn(yi, yj, __fmul_rn(xi, xj));
    float Ssum = __fadd_rn(sq_i, sqf[j]);
    float d2 = fmaxf(__fadd_rn(Ssum, -__fmul_rn(2.0f, dot2)), 0.0f);
    float arg = (-d2) / 5000.0f;
    float sp = (float)exp((double)arg);
    float u = __fmul_rn(__fadd_rn(__fmul_rn(lamf, accv), __fmul_rn(omlf, sp)), Tf);
    float e = (float)exp(-(double)u);
    candV[t] = 1.0f / __fadd_rn(1.0f, e);
  }
  __syncthreads();

  // --- selection: wave0 only, value desc, index asc (lax.top_k ties) ---
  if (t < 64) {
    for (int s = 0; s < KSEL; s++) {
      float bu = -1.0f; int bj = N, bs = 0;
      for (int c = t; c < ncand; c += 64) {
        float v = candV[c]; int j = candIdx[c];
        if (v > bu || (v == bu && j < bj)) { bu = v; bj = j; bs = c; }
      }
      #pragma unroll
      for (int off = 32; off > 0; off >>= 1) {
        float ov = __shfl_down(bu, off, 64);
        int   oj = __shfl_down(bj, off, 64);
        int   os = __shfl_down(bs, off, 64);
        if (ov > bu || (ov == bu && oj < bj)) { bu = ov; bj = oj; bs = os; }
      }
      if (t == 0) { selIdx[s] = bj; selVal[s] = bu; candV[bs] = -1.0f; }
      __builtin_amdgcn_s_waitcnt(0);
    }
  }
  __syncthreads();
  if (t < KSEL) orow[selIdx[t]] = selVal[t];
}

extern "C" void kernel_launch(void* const* d_in, const int* in_sizes, int n_in,
                              void* d_out, int out_size, void* d_ws, size_t ws_size,
                              hipStream_t stream) {
  const float* feat = (const float*)d_in[0];
  const float* pos  = (const float*)d_in[1];
  const float* lamw = (const float*)d_in[2];
  const float* temp = (const float*)d_in[3];
  float* out = (float*)d_out;
  unsigned int* out_u = (unsigned int*)d_out;

  float* normf = (float*)d_ws;
  float* sqf   = normf + N;
  float* fn32  = sqf + N;
  unsigned short* fnbf = (unsigned short*)(fn32 + (size_t)N * D);
  unsigned int* filtA = (unsigned int*)(fnbf + (size_t)N * D);
  size_t needA = (size_t)2 * N * 4 + (size_t)N * D * 4 + (size_t)N * D * 2 +
                 (size_t)N * FS_A * 4;

  prep_kernel<<<N / 32, 256, 0, stream>>>(feat, pos, lamw, normf, sqf,
                                          fn32, fnbf, out);
  if (ws_size >= needA) {
    adj_kernel<<<2080, 256, 0, stream>>>(fnbf, pos, sqf, lamw, temp,
                                         filtA, FS_A, out_u, 0);
    topk_kernel<<<N, 256, 0, stream>>>(pos, sqf, lamw, temp, fn32,
                                       filtA, FS_A, out, 0);
  } else {
    adj_kernel<<<2080, 256, 0, stream>>>(fnbf, pos, sqf, lamw, temp,
                                         out_u, ROWU, out_u, 1);
    topk_kernel<<<N, 256, 0, stream>>>(pos, sqf, lamw, temp, fn32,
                                       out_u, ROWU, out, 1);
  }
}